// Round 11
// baseline (1175.029 us; speedup 1.0000x reference)
//
#include <hip/hip_runtime.h>
#include <hip/hip_bf16.h>
#include <stdint.h>

typedef __bf16 bf16;
typedef __bf16 bf16x8 __attribute__((ext_vector_type(8)));
typedef float f32x4 __attribute__((ext_vector_type(4)));
typedef uint32_t u32x4 __attribute__((ext_vector_type(4)));

#define HD 128
#define LDP (HD + 8)
#define NTPB 4
#define MFMA __builtin_amdgcn_mfma_f32_16x16x32_bf16

__device__ inline float bflo(uint32_t u){ return __uint_as_float(u << 16); }
__device__ inline float bfhi(uint32_t u){ return __uint_as_float(u & 0xffff0000u); }
__device__ inline uint32_t packbf(float a, float b){
    bf16 x = (bf16)a, y = (bf16)b;
    uint16_t ux = __builtin_bit_cast(uint16_t, x), uy = __builtin_bit_cast(uint16_t, y);
    return (uint32_t)ux | ((uint32_t)uy << 16);
}
__device__ inline bf16x8 ldb8(const bf16* p){ return *(const bf16x8*)p; }
__device__ inline float sigm(float x){ return 1.f / (1.f + __expf(-x)); }
__device__ inline float tanh_fast(float x){ float t = __expf(-2.f * x); return (1.f - t) / (1.f + t); }
// 16B-slot swizzle within a 256B row: slot ^= row&7. Self-inverse.
__device__ inline uint32_t swz(uint32_t b){ return b ^ (((b >> 8) & 7u) << 4); }

// ---------------- weight conversion (plain) ----------------
__global__ void k_cvt(const float* __restrict__ in, bf16* __restrict__ out, int n){
    int i = blockIdx.x * 256 + threadIdx.x;
    if (i < n) out[i] = (bf16)in[i];
}

// ---------------- x conversion with per-row slot swizzle ----------------
__global__ void k_cvt_x(const float* __restrict__ in, uint32_t* __restrict__ out, int nU){
    int i = blockIdx.x * 256 + threadIdx.x;   // u32 index (2 bf16)
    if (i >= nU) return;
    int r = i >> 6, dw = i & 63;
    uint32_t v = packbf(in[(size_t)i * 2], in[(size_t)i * 2 + 1]);
    int slot = dw >> 2, w = dw & 3;
    out[(size_t)r * 64 + (((slot ^ (r & 7)) << 2) | w)] = v;
}

// ---------------- CSR (only the unsorted half needs building) ----------------
__global__ void k_bound(const int* __restrict__ dstB, int E, int* __restrict__ rows2, int n){
    int v = blockIdx.x * 256 + threadIdx.x;
    if (v > n) return;
    int lo = 0, hi = E;
    while (lo < hi){ int mid = (lo + hi) >> 1; if (dstB[mid] < v) lo = mid + 1; else hi = mid; }
    rows2[v] = lo;
}

__global__ void k_count(const int* __restrict__ dst, int* __restrict__ deg, int ne){
    int i = blockIdx.x * 256 + threadIdx.x;
    if (i < ne) atomicAdd(&deg[dst[i]], 1);
}

__global__ void k_scan1(const int* __restrict__ deg, int* __restrict__ rows,
                        int* __restrict__ bsum, int n){
    __shared__ int lds[256];
    int b = blockIdx.x, tid = threadIdx.x;
    int i0 = b * 1024 + tid * 4;
    int v[4]; int s = 0;
#pragma unroll
    for (int j = 0; j < 4; ++j){ int idx = i0 + j; v[j] = (idx < n) ? deg[idx] : 0; s += v[j]; }
    lds[tid] = s; __syncthreads();
    int acc = s;
    for (int off = 1; off < 256; off <<= 1){
        int add = (tid >= off) ? lds[tid - off] : 0;
        __syncthreads();
        acc += add; lds[tid] = acc;
        __syncthreads();
    }
    int run = acc - s;
#pragma unroll
    for (int j = 0; j < 4; ++j){ int idx = i0 + j; if (idx < n) rows[idx] = run; run += v[j]; }
    if (tid == 255) bsum[b] = acc;
}

__global__ void k_scan2(int* __restrict__ bsum, int nb){
    __shared__ int lds[128];
    int tid = threadIdx.x;
    int v = (tid < nb) ? bsum[tid] : 0;
    lds[tid] = v; __syncthreads();
    int acc = v;
    for (int off = 1; off < 128; off <<= 1){
        int add = (tid >= off) ? lds[tid - off] : 0;
        __syncthreads();
        acc += add; lds[tid] = acc;
        __syncthreads();
    }
    if (tid < nb) bsum[tid] = acc - v;
}

__global__ void k_scan3(int* __restrict__ rows, const int* __restrict__ bsum, int n, int total){
    int i = blockIdx.x * 256 + threadIdx.x;
    if (i < n) rows[i] += bsum[i >> 10];
    if (i == n) rows[n] = total;
}

// XCD-partitioned fill (writes to a col line come from one XCD -> stores merge)
__global__ void k_fillp(const int* __restrict__ src, const int* __restrict__ dst,
                        int* __restrict__ cur, int* __restrict__ col, int ne, int nPerG){
    int g = blockIdx.x & 7;
    int i = (blockIdx.x >> 3) * 256 + threadIdx.x;
    if (i >= ne) return;
    int d = dst[i];
    int lo = g * nPerG;
    if (d >= lo && d < lo + nPerG){
        int p = atomicAdd(&cur[d], 1);
        col[p] = src[i];
    }
}

// ---------------- mean aggregation over swizzled rows (round-7 verified version) ------
__global__ __launch_bounds__(256) void k_gather(
    const bf16* __restrict__ curx,
    const int* __restrict__ srcB, const int* __restrict__ rows2,
    const int* __restrict__ colB, const int* __restrict__ rowsB,
    bf16* __restrict__ cout, int n)
{
    int wid = threadIdx.x >> 6, lane = threadIdx.x & 63;
    int v = blockIdx.x * 4 + wid;
    if (v >= n) return;
    int grp = lane >> 3, sl = lane & 7;
    int a0 = rows2[v], a1 = rows2[v + 1];
    int b0 = rowsB[v], b1 = rowsB[v + 1];
    int deg = (a1 - a0) + (b1 - b0);
    float inv = (deg > 0) ? 1.f / (float)deg : 0.f;

    const u32x4* base = (const u32x4*)curx;
    float acc[16];
#pragma unroll
    for (int k = 0; k < 16; ++k) acc[k] = 0.f;

    for (int j = a0 + grp; j < a1; j += 8){
        int nb = srcB[j];
        int px = nb & 7;
        u32x4 q0 = base[(size_t)nb * 16 + (sl ^ px)];
        u32x4 q1 = base[(size_t)nb * 16 + 8 + (sl ^ px)];
#pragma unroll
        for (int k = 0; k < 4; ++k){
            acc[2*k]   += bflo(q0[k]); acc[2*k+1]   += bfhi(q0[k]);
            acc[8+2*k] += bflo(q1[k]); acc[8+2*k+1] += bfhi(q1[k]);
        }
    }
    for (int j = b0 + grp; j < b1; j += 8){
        int nb = colB[j];
        int px = nb & 7;
        u32x4 q0 = base[(size_t)nb * 16 + (sl ^ px)];
        u32x4 q1 = base[(size_t)nb * 16 + 8 + (sl ^ px)];
#pragma unroll
        for (int k = 0; k < 4; ++k){
            acc[2*k]   += bflo(q0[k]); acc[2*k+1]   += bfhi(q0[k]);
            acc[8+2*k] += bflo(q1[k]); acc[8+2*k+1] += bfhi(q1[k]);
        }
    }
#pragma unroll
    for (int k = 0; k < 16; ++k){
        acc[k] += __shfl_xor(acc[k], 8);
        acc[k] += __shfl_xor(acc[k], 16);
        acc[k] += __shfl_xor(acc[k], 32);
    }
    if (grp == 0){
        int pv = v & 7;
        u32x4 x0 = base[(size_t)v * 16 + (sl ^ pv)];
        u32x4 x1 = base[(size_t)v * 16 + 8 + (sl ^ pv)];
        u32x4 o0, o1;
#pragma unroll
        for (int k = 0; k < 4; ++k){
            o0[k] = packbf(bflo(x0[k]) + acc[2*k] * inv,   bfhi(x0[k]) + acc[2*k+1] * inv);
            o1[k] = packbf(bflo(x1[k]) + acc[8+2*k] * inv, bfhi(x1[k]) + acc[8+2*k+1] * inv);
        }
        ((u32x4*)cout)[(size_t)v * 16 + (sl ^ pv)]     = o0;
        ((u32x4*)cout)[(size_t)v * 16 + 8 + (sl ^ pv)] = o1;
    }
}

// ---------------- fused Layer v3: 64-row tiles, 48KB LDS -> 3 blocks/CU ----------------
// Same proven dataflow (GEMM1 C->A | GEMM2 A->C | GRU C,H->A | copyout), single-buffer
// in-place. All vmem waits consolidated: one counted vmcnt(2) at loop end (stage loads
// landed, 2 stores stay in flight). Mid barriers are lgkm-only -> no full drains.
#define NR   64
#define CBUF 0u
#define HBUF 16384u
#define ABUF 32768u
__global__ __launch_bounds__(512, 4) void k_layer(
    const bf16* __restrict__ cin, const bf16* __restrict__ hOld, bf16* __restrict__ hNew,
    const bf16* __restrict__ W1, const float* __restrict__ b1,
    const bf16* __restrict__ W2, const float* __restrict__ b2,
    const float* __restrict__ gm, const float* __restrict__ bt,
    const float* __restrict__ mu, const float* __restrict__ vr,
    const bf16* __restrict__ Wih, const bf16* __restrict__ Whh,
    const float* __restrict__ bih, const float* __restrict__ bhh, int nT)
{
    __shared__ __align__(16) char smem[49152];
    int tid = threadIdx.x, wid = tid >> 6, lane = tid & 63;
    int rA = lane & 15, u = lane >> 4, ko = u * 8;
    int c = wid * 16 + rA;                        // this lane's output column

    // ---- weights -> registers (once per block; per-wave 16-col slices) ----
    bf16x8 W1f[4], W2f[4], Gri[4], Grh[4], Gzi[4], Gzh[4], Gni[4], Gnh[4];
#pragma unroll
    for (int kk = 0; kk < 4; ++kk){
        W1f[kk] = ldb8(W1  + (size_t)c * HD + ko + kk * 32);
        W2f[kk] = ldb8(W2  + (size_t)c * HD + ko + kk * 32);
        Gri[kk] = ldb8(Wih + (size_t)c * HD + ko + kk * 32);
        Gzi[kk] = ldb8(Wih + (size_t)(c + 128) * HD + ko + kk * 32);
        Gni[kk] = ldb8(Wih + (size_t)(c + 256) * HD + ko + kk * 32);
        Grh[kk] = ldb8(Whh + (size_t)c * HD + ko + kk * 32);
        Gzh[kk] = ldb8(Whh + (size_t)(c + 128) * HD + ko + kk * 32);
        Gnh[kk] = ldb8(Whh + (size_t)(c + 256) * HD + ko + kk * 32);
    }
    float b1c = b1[c];
    float bnS = gm[c] * rsqrtf(vr[c] + 1e-5f);
    float bnO = bt[c] - mu[c] * bnS;
    float b2c = b2[c];
    float br = bih[c] + bhh[c], bz = bih[c + 128] + bhh[c + 128];
    float bin = bih[c + 256], bhn = bhh[c + 256];

    auto gload = [&](const char* g, uint32_t lo){
        __builtin_amdgcn_global_load_lds(
            (const __attribute__((address_space(1))) void*)g,
            (__attribute__((address_space(3))) void*)(smem + lo), 16, 0, 0);
    };
    auto stageC = [&](int t){
        const char* g = (const char*)cin + (size_t)t * 16384 + (size_t)lane * 16;
#pragma unroll
        for (int i = 0; i < 2; ++i){
            uint32_t ch = (uint32_t)(wid * 2 + i) * 1024;
            gload(g + ch, CBUF + ch);
        }
    };
    auto stageH = [&](int t){
        const char* g = (const char*)hOld + (size_t)t * 16384 + (size_t)lane * 16;
#pragma unroll
        for (int i = 0; i < 2; ++i){
            uint32_t ch = (uint32_t)(wid * 2 + i) * 1024;
            gload(g + ch, HBUF + ch);
        }
    };

    int t0 = blockIdx.x;
    if (t0 < nT){ stageC(t0); stageH(t0); }
    asm volatile("s_waitcnt vmcnt(0) lgkmcnt(0)" ::: "memory");
    __builtin_amdgcn_sched_barrier(0);
    __builtin_amdgcn_s_barrier();

    for (int t = t0; t < nT; t += (int)gridDim.x){
        // ---- GEMM1 + ReLU: C -> A ----
#pragma unroll
        for (int m = 0; m < 4; ++m){
            bf16x8 a_[4];
#pragma unroll
            for (int kk = 0; kk < 4; ++kk){
                uint32_t b = (uint32_t)(m * 16 + rA) * 256 + (uint32_t)(u * 16 + kk * 64);
                a_[kk] = *(const bf16x8*)(smem + CBUF + swz(b));
            }
            f32x4 acc = {0,0,0,0};
#pragma unroll
            for (int kk = 0; kk < 4; ++kk) acc = MFMA(a_[kk], W1f[kk], acc, 0, 0, 0);
#pragma unroll
            for (int j = 0; j < 4; ++j){
                uint32_t r = (uint32_t)(m * 16 + u * 4 + j);
                *(bf16*)(smem + ABUF + swz(r * 256 + (uint32_t)c * 2)) =
                    (bf16)fmaxf(acc[j] + b1c, 0.f);
            }
        }
        asm volatile("s_waitcnt lgkmcnt(0)" ::: "memory");
        __builtin_amdgcn_sched_barrier(0);
        __builtin_amdgcn_s_barrier();

        // ---- GEMM2 + BN: A -> C (c(t) fully consumed, in-place) ----
#pragma unroll
        for (int m = 0; m < 4; ++m){
            bf16x8 a_[4];
#pragma unroll
            for (int kk = 0; kk < 4; ++kk){
                uint32_t b = (uint32_t)(m * 16 + rA) * 256 + (uint32_t)(u * 16 + kk * 64);
                a_[kk] = *(const bf16x8*)(smem + ABUF + swz(b));
            }
            f32x4 acc = {0,0,0,0};
#pragma unroll
            for (int kk = 0; kk < 4; ++kk) acc = MFMA(a_[kk], W2f[kk], acc, 0, 0, 0);
#pragma unroll
            for (int j = 0; j < 4; ++j){
                uint32_t r = (uint32_t)(m * 16 + u * 4 + j);
                *(bf16*)(smem + CBUF + swz(r * 256 + (uint32_t)c * 2)) =
                    (bf16)((acc[j] + b2c) * bnS + bnO);
            }
        }
        asm volatile("s_waitcnt lgkmcnt(0)" ::: "memory");
        __builtin_amdgcn_sched_barrier(0);
        __builtin_amdgcn_s_barrier();

        // ---- GRU: C,H -> A ----
#pragma unroll
        for (int m = 0; m < 4; ++m){
            bf16x8 ac_[4], ah_[4];
#pragma unroll
            for (int kk = 0; kk < 4; ++kk){
                uint32_t b = (uint32_t)(m * 16 + rA) * 256 + (uint32_t)(u * 16 + kk * 64);
                ac_[kk] = *(const bf16x8*)(smem + CBUF + swz(b));
                ah_[kk] = *(const bf16x8*)(smem + HBUF + swz(b));
            }
            f32x4 rr = {0,0,0,0}, zz = {0,0,0,0}, gi = {0,0,0,0}, gh = {0,0,0,0};
#pragma unroll
            for (int kk = 0; kk < 4; ++kk){
                rr = MFMA(ac_[kk], Gri[kk], rr, 0, 0, 0);
                rr = MFMA(ah_[kk], Grh[kk], rr, 0, 0, 0);
                zz = MFMA(ac_[kk], Gzi[kk], zz, 0, 0, 0);
                zz = MFMA(ah_[kk], Gzh[kk], zz, 0, 0, 0);
                gi = MFMA(ac_[kk], Gni[kk], gi, 0, 0, 0);
                gh = MFMA(ah_[kk], Gnh[kk], gh, 0, 0, 0);
            }
#pragma unroll
            for (int j = 0; j < 4; ++j){
                uint32_t r = (uint32_t)(m * 16 + u * 4 + j);
                uint32_t inner = swz(r * 256 + (uint32_t)c * 2);
                float hold = (float)*(const bf16*)(smem + HBUF + inner);
                float rg = sigm(rr[j] + br);
                float zg = sigm(zz[j] + bz);
                float ng = tanh_fast(gi[j] + bin + rg * (gh[j] + bhn));
                *(bf16*)(smem + ABUF + inner) = (bf16)((1.f - zg) * ng + zg * hold);
            }
        }
        asm volatile("s_waitcnt lgkmcnt(0)" ::: "memory");
        __builtin_amdgcn_sched_barrier(0);
        __builtin_amdgcn_s_barrier();

        // ---- stage next tile into dead C/H, coalesced copy-out A -> hNew ----
        int tn = t + (int)gridDim.x;
        if (tn < nT){ stageC(tn); stageH(tn); }
        {
            char* hNb = (char*)hNew + (size_t)t * 16384;
#pragma unroll
            for (int i = 0; i < 2; ++i){
                uint32_t off = (uint32_t)tid * 16 + (uint32_t)i * 8192;
                *(u32x4*)(hNb + off) = *(const u32x4*)(smem + ABUF + off);
            }
        }
        // stage loads (4/thread, older) drained; 2 stores stay in flight
        asm volatile("s_waitcnt vmcnt(2) lgkmcnt(0)" ::: "memory");
        __builtin_amdgcn_sched_barrier(0);
        __builtin_amdgcn_s_barrier();
    }
}

// ---------------- final MLP: 128 -> 128 (ReLU) -> 64, f32 out ----------------
__global__ __launch_bounds__(256) void k_final(
    const bf16* __restrict__ hin, const bf16* __restrict__ W1, const float* __restrict__ b1,
    const bf16* __restrict__ W2, const float* __restrict__ b2,
    float* __restrict__ out, int nTiles)
{
    __shared__ bf16 lds[NTPB][16][LDP];
    int wid = threadIdx.x >> 6, lane = threadIdx.x & 63;
    int tile = blockIdx.x * NTPB + wid;
    if (tile >= nTiles) return;
    int r0 = tile * 16;
    int rA = lane & 15, u = lane >> 4, ko = u * 8;

    bf16x8 a[4];
    const char* hb = (const char*)hin;
    uint32_t b0 = (uint32_t)(r0 + rA) * 256 + (uint32_t)(u * 16);
#pragma unroll
    for (int kk = 0; kk < 4; ++kk) a[kk] = *(const bf16x8*)(hb + swz(b0 + (uint32_t)kk * 64));

#pragma unroll
    for (int t = 0; t < 8; ++t){
        f32x4 acc = {0.f, 0.f, 0.f, 0.f};
        int c = t * 16 + rA;
        const bf16* bp = W1 + (size_t)c * HD + ko;
#pragma unroll
        for (int kk = 0; kk < 4; ++kk)
            acc = MFMA(a[kk], ldb8(bp + kk * 32), acc, 0, 0, 0);
        float bias = b1[c];
#pragma unroll
        for (int j = 0; j < 4; ++j){
            float v = fmaxf(acc[j] + bias, 0.f);
            lds[wid][u * 4 + j][c] = (bf16)v;
        }
    }
    __threadfence_block();
    bf16x8 a2[4];
    const bf16* lp = &lds[wid][rA][ko];
#pragma unroll
    for (int kk = 0; kk < 4; ++kk) a2[kk] = ldb8(lp + kk * 32);

#pragma unroll
    for (int t = 0; t < 4; ++t){
        f32x4 acc = {0.f, 0.f, 0.f, 0.f};
        int c = t * 16 + rA;
        const bf16* bp = W2 + (size_t)c * HD + ko;
#pragma unroll
        for (int kk = 0; kk < 4; ++kk)
            acc = MFMA(a2[kk], ldb8(bp + kk * 32), acc, 0, 0, 0);
        float bias = b2[c];
#pragma unroll
        for (int j = 0; j < 4; ++j)
            out[(size_t)(r0 + u * 4 + j) * 64 + c] = acc[j] + bias;
    }
}

extern "C" void kernel_launch(void* const* d_in, const int* in_sizes, int n_in,
                              void* d_out, int out_size, void* d_ws, size_t ws_size,
                              hipStream_t stream)
{
    const float* x    = (const float*)d_in[0];
    const int*   src  = (const int*)d_in[1];
    const int*   dst  = (const int*)d_in[2];
    const float* lW1  = (const float*)d_in[3];
    const float* lb1  = (const float*)d_in[4];
    const float* lW2  = (const float*)d_in[5];
    const float* lb2  = (const float*)d_in[6];
    const float* gmm  = (const float*)d_in[7];
    const float* bta  = (const float*)d_in[8];
    const float* mun  = (const float*)d_in[9];
    const float* vrr  = (const float*)d_in[10];
    const float* Wih  = (const float*)d_in[11];
    const float* Whh  = (const float*)d_in[12];
    const float* bih  = (const float*)d_in[13];
    const float* bhh  = (const float*)d_in[14];
    const float* fW1  = (const float*)d_in[15];
    const float* fb1  = (const float*)d_in[16];
    const float* fW2  = (const float*)d_in[17];
    const float* fb2  = (const float*)d_in[18];

    int n  = in_sizes[0] / HD;
    int ne = in_sizes[1];
    int E  = ne / 2;                    // dst[E:2E) is sorted
    int L  = in_sizes[3] / (HD * HD);
    int nPad = (n + 127) & ~127;

    char* w = (char*)d_ws;
    auto alloc = [&](size_t bytes) -> char* {
        char* p = w; w += (bytes + 255) & ~(size_t)255; return p;
    };
    bf16* xbf  = (bf16*)alloc((size_t)nPad * HD * 2);
    bf16* hA   = (bf16*)alloc((size_t)nPad * HD * 2);
    bf16* hB   = (bf16*)alloc((size_t)nPad * HD * 2);
    bf16* cin  = (bf16*)alloc((size_t)nPad * HD * 2);
    bf16* W1b  = (bf16*)alloc((size_t)L * HD * HD * 2);
    bf16* W2b  = (bf16*)alloc((size_t)L * HD * HD * 2);
    bf16* Wib  = (bf16*)alloc((size_t)3 * HD * HD * 2);
    bf16* Whb  = (bf16*)alloc((size_t)3 * HD * HD * 2);
    bf16* fW1b = (bf16*)alloc((size_t)HD * HD * 2);
    bf16* fW2b = (bf16*)alloc((size_t)64 * HD * 2);
    int*  degB = (int*)alloc((size_t)n * 4);
    int*  rowsB= (int*)alloc((size_t)(n + 1) * 4);
    int*  rows2= (int*)alloc((size_t)(n + 1) * 4);
    int*  bsum = (int*)alloc(512);
    int*  curB = (int*)alloc((size_t)n * 4);
    int*  colB = (int*)alloc((size_t)E * 4);

    auto cvt = [&](const float* i, bf16* o, int cnt){
        k_cvt<<<(cnt + 255) / 256, 256, 0, stream>>>(i, o, cnt);
    };
    int nU = n * 64;
    k_cvt_x<<<(nU + 255) / 256, 256, 0, stream>>>(x, (uint32_t*)xbf, nU);
    cvt(lW1, W1b,  L * HD * HD);
    cvt(lW2, W2b,  L * HD * HD);
    cvt(Wih, Wib,  3 * HD * HD);
    cvt(Whh, Whb,  3 * HD * HD);
    cvt(fW1, fW1b, HD * HD);
    cvt(fW2, fW2b, 64 * HD);

    hipMemsetAsync(degB, 0, (size_t)n * 4, stream);
    hipMemsetAsync(hA, 0, (size_t)nPad * HD * 2, stream);

    k_bound<<<(n + 1 + 255) / 256, 256, 0, stream>>>(dst + E, E, rows2, n);
    k_count<<<(E + 255) / 256, 256, 0, stream>>>(dst, degB, E);
    int nb = (n + 1023) / 1024;
    k_scan1<<<nb, 256, 0, stream>>>(degB, rowsB, bsum, n);
    k_scan2<<<1, 128, 0, stream>>>(bsum, nb);
    k_scan3<<<(n + 1 + 255) / 256, 256, 0, stream>>>(rowsB, bsum, n, E);
    hipMemcpyAsync(curB, rowsB, (size_t)n * 4, hipMemcpyDeviceToDevice, stream);
    int nPerG = (n + 7) / 8;
    k_fillp<<<8 * ((E + 255) / 256), 256, 0, stream>>>(src, dst, curB, colB, E, nPerG);

    int nT64 = nPad / 64;
    int gL = 768;                       // 3 blocks/CU
    if (gL > nT64) gL = nT64;
    int nT16 = (n + 15) / 16;
    int gF = (nT16 + NTPB - 1) / NTPB;

    const bf16* curp = xbf;
    for (int l = 0; l < L; ++l){
        k_gather<<<(n + 3) / 4, 256, 0, stream>>>(curp, src + E, rows2, colB, rowsB, cin, n);
        k_layer<<<gL, 512, 0, stream>>>(cin, hA, hB,
            W1b + (size_t)l * HD * HD, lb1 + l * HD,
            W2b + (size_t)l * HD * HD, lb2 + l * HD,
            gmm + l * HD, bta + l * HD, mun + l * HD, vrr + l * HD,
            Wib, Whb, bih, bhh, nT64);
        bf16* tmp = hA; hA = hB; hB = tmp;
        curp = hA;
    }
    k_final<<<gF, 256, 0, stream>>>(hA, fW1b, fb1, fW2b, fb2, (float*)d_out, nT16);
}

// Round 12
// 761.702 us; speedup vs baseline: 1.5426x; 1.5426x over previous
//
#include <hip/hip_runtime.h>
#include <hip/hip_bf16.h>
#include <stdint.h>

typedef __bf16 bf16;
typedef __bf16 bf16x8 __attribute__((ext_vector_type(8)));
typedef float f32x4 __attribute__((ext_vector_type(4)));
typedef float f32x2 __attribute__((ext_vector_type(2)));
typedef uint32_t u32x4 __attribute__((ext_vector_type(4)));

#define HD 128
#define LDP (HD + 8)
#define NTPB 4
#define MFMA __builtin_amdgcn_mfma_f32_16x16x32_bf16

__device__ inline float bflo(uint32_t u){ return __uint_as_float(u << 16); }
__device__ inline float bfhi(uint32_t u){ return __uint_as_float(u & 0xffff0000u); }
__device__ inline uint32_t packbf(float a, float b){
    bf16 x = (bf16)a, y = (bf16)b;
    uint16_t ux = __builtin_bit_cast(uint16_t, x), uy = __builtin_bit_cast(uint16_t, y);
    return (uint32_t)ux | ((uint32_t)uy << 16);
}
__device__ inline bf16x8 ldb8(const bf16* p){ return *(const bf16x8*)p; }
__device__ inline float sigm(float x){ return 1.f / (1.f + __expf(-x)); }
__device__ inline float tanh_fast(float x){ float t = __expf(-2.f * x); return (1.f - t) / (1.f + t); }
// 16B-slot swizzle within a 256B row: slot ^= row&7. Self-inverse.
__device__ inline uint32_t swz(uint32_t b){ return b ^ (((b >> 8) & 7u) << 4); }

// ---------------- weight conversion (plain) ----------------
__global__ void k_cvt(const float* __restrict__ in, bf16* __restrict__ out, int n){
    int i = blockIdx.x * 256 + threadIdx.x;
    if (i < n) out[i] = (bf16)in[i];
}

// ---------------- x conversion with per-row slot swizzle ----------------
__global__ void k_cvt_x(const float* __restrict__ in, uint32_t* __restrict__ out, int nU){
    int i = blockIdx.x * 256 + threadIdx.x;   // u32 index (2 bf16)
    if (i >= nU) return;
    int r = i >> 6, dw = i & 63;
    uint32_t v = packbf(in[(size_t)i * 2], in[(size_t)i * 2 + 1]);
    int slot = dw >> 2, w = dw & 3;
    out[(size_t)r * 64 + (((slot ^ (r & 7)) << 2) | w)] = v;
}

// ---------------- CSR (only the unsorted half needs building) ----------------
__global__ void k_bound(const int* __restrict__ dstB, int E, int* __restrict__ rows2, int n){
    int v = blockIdx.x * 256 + threadIdx.x;
    if (v > n) return;
    int lo = 0, hi = E;
    while (lo < hi){ int mid = (lo + hi) >> 1; if (dstB[mid] < v) lo = mid + 1; else hi = mid; }
    rows2[v] = lo;
}

__global__ void k_count(const int* __restrict__ dst, int* __restrict__ deg, int ne){
    int i = blockIdx.x * 256 + threadIdx.x;
    if (i < ne) atomicAdd(&deg[dst[i]], 1);
}

__global__ void k_scan1(const int* __restrict__ deg, int* __restrict__ rows,
                        int* __restrict__ bsum, int n){
    __shared__ int lds[256];
    int b = blockIdx.x, tid = threadIdx.x;
    int i0 = b * 1024 + tid * 4;
    int v[4]; int s = 0;
#pragma unroll
    for (int j = 0; j < 4; ++j){ int idx = i0 + j; v[j] = (idx < n) ? deg[idx] : 0; s += v[j]; }
    lds[tid] = s; __syncthreads();
    int acc = s;
    for (int off = 1; off < 256; off <<= 1){
        int add = (tid >= off) ? lds[tid - off] : 0;
        __syncthreads();
        acc += add; lds[tid] = acc;
        __syncthreads();
    }
    int run = acc - s;
#pragma unroll
    for (int j = 0; j < 4; ++j){ int idx = i0 + j; if (idx < n) rows[idx] = run; run += v[j]; }
    if (tid == 255) bsum[b] = acc;
}

__global__ void k_scan2(int* __restrict__ bsum, int nb){
    __shared__ int lds[128];
    int tid = threadIdx.x;
    int v = (tid < nb) ? bsum[tid] : 0;
    lds[tid] = v; __syncthreads();
    int acc = v;
    for (int off = 1; off < 128; off <<= 1){
        int add = (tid >= off) ? lds[tid - off] : 0;
        __syncthreads();
        acc += add; lds[tid] = acc;
        __syncthreads();
    }
    if (tid < nb) bsum[tid] = acc - v;
}

__global__ void k_scan3(int* __restrict__ rows, const int* __restrict__ bsum, int n, int total){
    int i = blockIdx.x * 256 + threadIdx.x;
    if (i < n) rows[i] += bsum[i >> 10];
    if (i == n) rows[n] = total;
}

// XCD-partitioned fill (writes to a col line come from one XCD -> stores merge)
__global__ void k_fillp(const int* __restrict__ src, const int* __restrict__ dst,
                        int* __restrict__ cur, int* __restrict__ col, int ne, int nPerG){
    int g = blockIdx.x & 7;
    int i = (blockIdx.x >> 3) * 256 + threadIdx.x;
    if (i >= ne) return;
    int d = dst[i];
    int lo = g * nPerG;
    if (d >= lo && d < lo + nPerG){
        int p = atomicAdd(&cur[d], 1);
        col[p] = src[i];
    }
}

// ---------------- mean aggregation over swizzled rows (packed f32 accumulate) ------
__global__ __launch_bounds__(256) void k_gather(
    const bf16* __restrict__ curx,
    const int* __restrict__ srcB, const int* __restrict__ rows2,
    const int* __restrict__ colB, const int* __restrict__ rowsB,
    bf16* __restrict__ cout, int n)
{
    int wid = threadIdx.x >> 6, lane = threadIdx.x & 63;
    int v = blockIdx.x * 4 + wid;
    if (v >= n) return;
    int grp = lane >> 3, sl = lane & 7;
    int a0 = rows2[v], a1 = rows2[v + 1];
    int b0 = rowsB[v], b1 = rowsB[v + 1];
    int deg = (a1 - a0) + (b1 - b0);
    float inv = (deg > 0) ? 1.f / (float)deg : 0.f;

    const u32x4* base = (const u32x4*)curx;
    f32x2 acc2[8];
#pragma unroll
    for (int k = 0; k < 8; ++k) acc2[k] = (f32x2){0.f, 0.f};

    for (int j = a0 + grp; j < a1; j += 8){
        int nb = srcB[j];
        int px = nb & 7;
        u32x4 q0 = base[(size_t)nb * 16 + (sl ^ px)];
        u32x4 q1 = base[(size_t)nb * 16 + 8 + (sl ^ px)];
#pragma unroll
        for (int k = 0; k < 4; ++k){
            acc2[k]     += (f32x2){bflo(q0[k]), bfhi(q0[k])};   // v_pk_add_f32
            acc2[4 + k] += (f32x2){bflo(q1[k]), bfhi(q1[k])};
        }
    }
    for (int j = b0 + grp; j < b1; j += 8){
        int nb = colB[j];
        int px = nb & 7;
        u32x4 q0 = base[(size_t)nb * 16 + (sl ^ px)];
        u32x4 q1 = base[(size_t)nb * 16 + 8 + (sl ^ px)];
#pragma unroll
        for (int k = 0; k < 4; ++k){
            acc2[k]     += (f32x2){bflo(q0[k]), bfhi(q0[k])};
            acc2[4 + k] += (f32x2){bflo(q1[k]), bfhi(q1[k])};
        }
    }
    // unpack to scalars for the cross-lane reduce (one-time)
    float acc[16];
#pragma unroll
    for (int k = 0; k < 4; ++k){
        acc[2*k]     = acc2[k].x;     acc[2*k+1]     = acc2[k].y;
        acc[8+2*k]   = acc2[4+k].x;   acc[8+2*k+1]   = acc2[4+k].y;
    }
#pragma unroll
    for (int k = 0; k < 16; ++k){
        acc[k] += __shfl_xor(acc[k], 8);
        acc[k] += __shfl_xor(acc[k], 16);
        acc[k] += __shfl_xor(acc[k], 32);
    }
    if (grp == 0){
        int pv = v & 7;
        u32x4 x0 = base[(size_t)v * 16 + (sl ^ pv)];
        u32x4 x1 = base[(size_t)v * 16 + 8 + (sl ^ pv)];
        u32x4 o0, o1;
#pragma unroll
        for (int k = 0; k < 4; ++k){
            o0[k] = packbf(bflo(x0[k]) + acc[2*k] * inv,   bfhi(x0[k]) + acc[2*k+1] * inv);
            o1[k] = packbf(bflo(x1[k]) + acc[8+2*k] * inv, bfhi(x1[k]) + acc[8+2*k+1] * inv);
        }
        ((u32x4*)cout)[(size_t)v * 16 + (sl ^ pv)]     = o0;
        ((u32x4*)cout)[(size_t)v * 16 + 8 + (sl ^ pv)] = o1;
    }
}

// ---------------- fused Layer (round-8 verified): wave-stationary weights, 128-row tiles,
// 128KB LDS, (512,1) so the 128 weight VGPRs stay resident (r11 showed (512,4) spills). ----
#define CL0 0u
#define CL1 32768u
#define HL0 65536u
#define ALO 98304u
__global__ __launch_bounds__(512, 1) void k_layer(
    const bf16* __restrict__ cin, const bf16* __restrict__ hOld, bf16* __restrict__ hNew,
    const bf16* __restrict__ W1, const float* __restrict__ b1,
    const bf16* __restrict__ W2, const float* __restrict__ b2,
    const float* __restrict__ gm, const float* __restrict__ bt,
    const float* __restrict__ mu, const float* __restrict__ vr,
    const bf16* __restrict__ Wih, const bf16* __restrict__ Whh,
    const float* __restrict__ bih, const float* __restrict__ bhh, int nT)
{
    __shared__ __align__(16) char smem[131072];
    int tid = threadIdx.x, wid = tid >> 6, lane = tid & 63;
    int rA = lane & 15, u = lane >> 4, ko = u * 8;
    int c = wid * 16 + rA;

    bf16x8 W1f[4], W2f[4], Gri[4], Grh[4], Gzi[4], Gzh[4], Gni[4], Gnh[4];
#pragma unroll
    for (int kk = 0; kk < 4; ++kk){
        W1f[kk] = ldb8(W1  + (size_t)c * HD + ko + kk * 32);
        W2f[kk] = ldb8(W2  + (size_t)c * HD + ko + kk * 32);
        Gri[kk] = ldb8(Wih + (size_t)c * HD + ko + kk * 32);
        Gzi[kk] = ldb8(Wih + (size_t)(c + 128) * HD + ko + kk * 32);
        Gni[kk] = ldb8(Wih + (size_t)(c + 256) * HD + ko + kk * 32);
        Grh[kk] = ldb8(Whh + (size_t)c * HD + ko + kk * 32);
        Gzh[kk] = ldb8(Whh + (size_t)(c + 128) * HD + ko + kk * 32);
        Gnh[kk] = ldb8(Whh + (size_t)(c + 256) * HD + ko + kk * 32);
    }
    float b1c = b1[c];
    float bnS = gm[c] * rsqrtf(vr[c] + 1e-5f);
    float bnO = bt[c] - mu[c] * bnS;
    float b2c = b2[c];
    float br = bih[c] + bhh[c], bz = bih[c + 128] + bhh[c + 128];
    float bin = bih[c + 256], bhn = bhh[c + 256];

    auto gload = [&](const char* g, uint32_t lo){
        __builtin_amdgcn_global_load_lds(
            (const __attribute__((address_space(1))) void*)g,
            (__attribute__((address_space(3))) void*)(smem + lo), 16, 0, 0);
    };
    auto stageC = [&](int t, uint32_t dst){
        const char* g = (const char*)cin + (size_t)t * 32768 + (size_t)lane * 16;
#pragma unroll
        for (int i = 0; i < 4; ++i){
            uint32_t ch = (uint32_t)(wid * 4 + i) * 1024;
            gload(g + ch, dst + ch);
        }
    };
    auto stageH = [&](int t){
        const char* g = (const char*)hOld + (size_t)t * 32768 + (size_t)lane * 16;
#pragma unroll
        for (int i = 0; i < 4; ++i){
            uint32_t ch = (uint32_t)(wid * 4 + i) * 1024;
            gload(g + ch, HL0 + ch);
        }
    };

    int t = blockIdx.x;
    int cur = 0;
    if (t < nT) stageC(t, CL0);
    for (; t < nT; t += (int)gridDim.x){
        __syncthreads();
        stageH(t);
        int tn = t + (int)gridDim.x;
        if (tn < nT) stageC(tn, cur ? CL0 : CL1);
        uint32_t CB = cur ? CL1 : CL0;

#pragma unroll
        for (int m = 0; m < 8; ++m){
            bf16x8 a_[4];
#pragma unroll
            for (int kk = 0; kk < 4; ++kk){
                uint32_t b = (uint32_t)(m * 16 + rA) * 256 + (uint32_t)(u * 16 + kk * 64);
                a_[kk] = *(const bf16x8*)(smem + CB + swz(b));
            }
            f32x4 acc = {0,0,0,0};
#pragma unroll
            for (int kk = 0; kk < 4; ++kk) acc = MFMA(a_[kk], W1f[kk], acc, 0, 0, 0);
#pragma unroll
            for (int j = 0; j < 4; ++j){
                uint32_t r = (uint32_t)(m * 16 + u * 4 + j);
                *(bf16*)(smem + ALO + swz(r * 256 + (uint32_t)c * 2)) =
                    (bf16)fmaxf(acc[j] + b1c, 0.f);
            }
        }
        asm volatile("s_waitcnt lgkmcnt(0)" ::: "memory");
        __builtin_amdgcn_sched_barrier(0);
        __builtin_amdgcn_s_barrier();

#pragma unroll
        for (int m = 0; m < 8; ++m){
            bf16x8 a_[4];
#pragma unroll
            for (int kk = 0; kk < 4; ++kk){
                uint32_t b = (uint32_t)(m * 16 + rA) * 256 + (uint32_t)(u * 16 + kk * 64);
                a_[kk] = *(const bf16x8*)(smem + ALO + swz(b));
            }
            f32x4 acc = {0,0,0,0};
#pragma unroll
            for (int kk = 0; kk < 4; ++kk) acc = MFMA(a_[kk], W2f[kk], acc, 0, 0, 0);
#pragma unroll
            for (int j = 0; j < 4; ++j){
                uint32_t r = (uint32_t)(m * 16 + u * 4 + j);
                *(bf16*)(smem + CB + swz(r * 256 + (uint32_t)c * 2)) =
                    (bf16)((acc[j] + b2c) * bnS + bnO);
            }
        }
        if (tn < nT){ asm volatile("s_waitcnt vmcnt(4) lgkmcnt(0)" ::: "memory"); }
        else        { asm volatile("s_waitcnt vmcnt(0) lgkmcnt(0)" ::: "memory"); }
        __builtin_amdgcn_sched_barrier(0);
        __builtin_amdgcn_s_barrier();

#pragma unroll
        for (int m = 0; m < 8; ++m){
            bf16x8 ac_[4], ah_[4];
#pragma unroll
            for (int kk = 0; kk < 4; ++kk){
                uint32_t b = (uint32_t)(m * 16 + rA) * 256 + (uint32_t)(u * 16 + kk * 64);
                ac_[kk] = *(const bf16x8*)(smem + CB + swz(b));
                ah_[kk] = *(const bf16x8*)(smem + HL0 + swz(b));
            }
            f32x4 rr = {0,0,0,0}, zz = {0,0,0,0}, gi = {0,0,0,0}, gh = {0,0,0,0};
#pragma unroll
            for (int kk = 0; kk < 4; ++kk){
                rr = MFMA(ac_[kk], Gri[kk], rr, 0, 0, 0);
                rr = MFMA(ah_[kk], Grh[kk], rr, 0, 0, 0);
                zz = MFMA(ac_[kk], Gzi[kk], zz, 0, 0, 0);
                zz = MFMA(ah_[kk], Gzh[kk], zz, 0, 0, 0);
                gi = MFMA(ac_[kk], Gni[kk], gi, 0, 0, 0);
                gh = MFMA(ah_[kk], Gnh[kk], gh, 0, 0, 0);
            }
#pragma unroll
            for (int j = 0; j < 4; ++j){
                uint32_t r = (uint32_t)(m * 16 + u * 4 + j);
                uint32_t inner = swz(r * 256 + (uint32_t)c * 2);
                float hold = (float)*(const bf16*)(smem + HL0 + inner);
                float rg = sigm(rr[j] + br);
                float zg = sigm(zz[j] + bz);
                float ng = tanh_fast(gi[j] + bin + rg * (gh[j] + bhn));
                *(bf16*)(smem + ALO + inner) = (bf16)((1.f - zg) * ng + zg * hold);
            }
        }
        asm volatile("s_waitcnt lgkmcnt(0)" ::: "memory");
        __builtin_amdgcn_sched_barrier(0);
        __builtin_amdgcn_s_barrier();

        {
            char* hNb = (char*)hNew + (size_t)t * 32768;
#pragma unroll
            for (int i = 0; i < 4; ++i){
                uint32_t off = (uint32_t)tid * 16 + (uint32_t)i * 8192;
                *(u32x4*)(hNb + off) = *(const u32x4*)(smem + ALO + off);
            }
        }
        cur ^= 1;
    }
}

// ---------------- final MLP: 128 -> 128 (ReLU) -> 64, f32 out ----------------
__global__ __launch_bounds__(256) void k_final(
    const bf16* __restrict__ hin, const bf16* __restrict__ W1, const float* __restrict__ b1,
    const bf16* __restrict__ W2, const float* __restrict__ b2,
    float* __restrict__ out, int nTiles)
{
    __shared__ bf16 lds[NTPB][16][LDP];
    int wid = threadIdx.x >> 6, lane = threadIdx.x & 63;
    int tile = blockIdx.x * NTPB + wid;
    if (tile >= nTiles) return;
    int r0 = tile * 16;
    int rA = lane & 15, u = lane >> 4, ko = u * 8;

    bf16x8 a[4];
    const char* hb = (const char*)hin;
    uint32_t b0 = (uint32_t)(r0 + rA) * 256 + (uint32_t)(u * 16);
#pragma unroll
    for (int kk = 0; kk < 4; ++kk) a[kk] = *(const bf16x8*)(hb + swz(b0 + (uint32_t)kk * 64));

#pragma unroll
    for (int t = 0; t < 8; ++t){
        f32x4 acc = {0.f, 0.f, 0.f, 0.f};
        int c = t * 16 + rA;
        const bf16* bp = W1 + (size_t)c * HD + ko;
#pragma unroll
        for (int kk = 0; kk < 4; ++kk)
            acc = MFMA(a[kk], ldb8(bp + kk * 32), acc, 0, 0, 0);
        float bias = b1[c];
#pragma unroll
        for (int j = 0; j < 4; ++j){
            float v = fmaxf(acc[j] + bias, 0.f);
            lds[wid][u * 4 + j][c] = (bf16)v;
        }
    }
    __threadfence_block();
    bf16x8 a2[4];
    const bf16* lp = &lds[wid][rA][ko];
#pragma unroll
    for (int kk = 0; kk < 4; ++kk) a2[kk] = ldb8(lp + kk * 32);

#pragma unroll
    for (int t = 0; t < 4; ++t){
        f32x4 acc = {0.f, 0.f, 0.f, 0.f};
        int c = t * 16 + rA;
        const bf16* bp = W2 + (size_t)c * HD + ko;
#pragma unroll
        for (int kk = 0; kk < 4; ++kk)
            acc = MFMA(a2[kk], ldb8(bp + kk * 32), acc, 0, 0, 0);
        float bias = b2[c];
#pragma unroll
        for (int j = 0; j < 4; ++j)
            out[(size_t)(r0 + u * 4 + j) * 64 + c] = acc[j] + bias;
    }
}

extern "C" void kernel_launch(void* const* d_in, const int* in_sizes, int n_in,
                              void* d_out, int out_size, void* d_ws, size_t ws_size,
                              hipStream_t stream)
{
    const float* x    = (const float*)d_in[0];
    const int*   src  = (const int*)d_in[1];
    const int*   dst  = (const int*)d_in[2];
    const float* lW1  = (const float*)d_in[3];
    const float* lb1  = (const float*)d_in[4];
    const float* lW2  = (const float*)d_in[5];
    const float* lb2  = (const float*)d_in[6];
    const float* gmm  = (const float*)d_in[7];
    const float* bta  = (const float*)d_in[8];
    const float* mun  = (const float*)d_in[9];
    const float* vrr  = (const float*)d_in[10];
    const float* Wih  = (const float*)d_in[11];
    const float* Whh  = (const float*)d_in[12];
    const float* bih  = (const float*)d_in[13];
    const float* bhh  = (const float*)d_in[14];
    const float* fW1  = (const float*)d_in[15];
    const float* fb1  = (const float*)d_in[16];
    const float* fW2  = (const float*)d_in[17];
    const float* fb2  = (const float*)d_in[18];

    int n  = in_sizes[0] / HD;
    int ne = in_sizes[1];
    int E  = ne / 2;                    // dst[E:2E) is sorted
    int L  = in_sizes[3] / (HD * HD);
    int nPad = (n + 127) & ~127;

    char* w = (char*)d_ws;
    auto alloc = [&](size_t bytes) -> char* {
        char* p = w; w += (bytes + 255) & ~(size_t)255; return p;
    };
    bf16* xbf  = (bf16*)alloc((size_t)nPad * HD * 2);
    bf16* hA   = (bf16*)alloc((size_t)nPad * HD * 2);
    bf16* hB   = (bf16*)alloc((size_t)nPad * HD * 2);
    bf16* cin  = (bf16*)alloc((size_t)nPad * HD * 2);
    bf16* W1b  = (bf16*)alloc((size_t)L * HD * HD * 2);
    bf16* W2b  = (bf16*)alloc((size_t)L * HD * HD * 2);
    bf16* Wib  = (bf16*)alloc((size_t)3 * HD * HD * 2);
    bf16* Whb  = (bf16*)alloc((size_t)3 * HD * HD * 2);
    bf16* fW1b = (bf16*)alloc((size_t)HD * HD * 2);
    bf16* fW2b = (bf16*)alloc((size_t)64 * HD * 2);
    int*  degB = (int*)alloc((size_t)n * 4);
    int*  rowsB= (int*)alloc((size_t)(n + 1) * 4);
    int*  rows2= (int*)alloc((size_t)(n + 1) * 4);
    int*  bsum = (int*)alloc(512);
    int*  curB = (int*)alloc((size_t)n * 4);
    int*  colB = (int*)alloc((size_t)E * 4);

    auto cvt = [&](const float* i, bf16* o, int cnt){
        k_cvt<<<(cnt + 255) / 256, 256, 0, stream>>>(i, o, cnt);
    };
    int nU = n * 64;
    k_cvt_x<<<(nU + 255) / 256, 256, 0, stream>>>(x, (uint32_t*)xbf, nU);
    cvt(lW1, W1b,  L * HD * HD);
    cvt(lW2, W2b,  L * HD * HD);
    cvt(Wih, Wib,  3 * HD * HD);
    cvt(Whh, Whb,  3 * HD * HD);
    cvt(fW1, fW1b, HD * HD);
    cvt(fW2, fW2b, 64 * HD);

    hipMemsetAsync(degB, 0, (size_t)n * 4, stream);
    hipMemsetAsync(hA, 0, (size_t)nPad * HD * 2, stream);

    k_bound<<<(n + 1 + 255) / 256, 256, 0, stream>>>(dst + E, E, rows2, n);
    k_count<<<(E + 255) / 256, 256, 0, stream>>>(dst, degB, E);
    int nb = (n + 1023) / 1024;
    k_scan1<<<nb, 256, 0, stream>>>(degB, rowsB, bsum, n);
    k_scan2<<<1, 128, 0, stream>>>(bsum, nb);
    k_scan3<<<(n + 1 + 255) / 256, 256, 0, stream>>>(rowsB, bsum, n, E);
    hipMemcpyAsync(curB, rowsB, (size_t)n * 4, hipMemcpyDeviceToDevice, stream);
    int nPerG = (n + 7) / 8;
    k_fillp<<<8 * ((E + 255) / 256), 256, 0, stream>>>(src, dst, curB, colB, E, nPerG);

    int nT128 = nPad / 128;
    int nT16 = (n + 15) / 16;
    int gF = (nT16 + NTPB - 1) / NTPB;

    const bf16* curp = xbf;
    for (int l = 0; l < L; ++l){
        k_gather<<<(n + 3) / 4, 256, 0, stream>>>(curp, src + E, rows2, colB, rowsB, cin, n);
        k_layer<<<256, 512, 0, stream>>>(cin, hA, hB,
            W1b + (size_t)l * HD * HD, lb1 + l * HD,
            W2b + (size_t)l * HD * HD, lb2 + l * HD,
            gmm + l * HD, bta + l * HD, mun + l * HD, vrr + l * HD,
            Wib, Whb, bih, bhh, nT128);
        bf16* tmp = hA; hA = hB; hB = tmp;
        curp = hA;
    }
    k_final<<<gF, 256, 0, stream>>>(hA, fW1b, fb1, fW2b, fb2, (float*)d_out, nT16);
}

// Round 13
// 748.035 us; speedup vs baseline: 1.5708x; 1.0183x over previous
//
#include <hip/hip_runtime.h>
#include <hip/hip_bf16.h>
#include <stdint.h>

typedef __bf16 bf16;
typedef __bf16 bf16x8 __attribute__((ext_vector_type(8)));
typedef float f32x4 __attribute__((ext_vector_type(4)));
typedef float f32x2 __attribute__((ext_vector_type(2)));
typedef uint32_t u32x4 __attribute__((ext_vector_type(4)));

#define HD 128
#define LDP (HD + 8)
#define NTPB 4
#define MFMA __builtin_amdgcn_mfma_f32_16x16x32_bf16

__device__ inline float bflo(uint32_t u){ return __uint_as_float(u << 16); }
__device__ inline float bfhi(uint32_t u){ return __uint_as_float(u & 0xffff0000u); }
__device__ inline uint32_t packbf(float a, float b){
    bf16 x = (bf16)a, y = (bf16)b;
    uint16_t ux = __builtin_bit_cast(uint16_t, x), uy = __builtin_bit_cast(uint16_t, y);
    return (uint32_t)ux | ((uint32_t)uy << 16);
}
__device__ inline bf16x8 ldb8(const bf16* p){ return *(const bf16x8*)p; }
__device__ inline float sigm(float x){ return 1.f / (1.f + __expf(-x)); }
__device__ inline float tanh_fast(float x){ float t = __expf(-2.f * x); return (1.f - t) / (1.f + t); }
// 16B-slot swizzle within a 256B row: slot ^= row&7. Self-inverse.
__device__ inline uint32_t swz(uint32_t b){ return b ^ (((b >> 8) & 7u) << 4); }

// ---------------- weight conversion (plain) ----------------
__global__ void k_cvt(const float* __restrict__ in, bf16* __restrict__ out, int n){
    int i = blockIdx.x * 256 + threadIdx.x;
    if (i < n) out[i] = (bf16)in[i];
}

// ---------------- x conversion with per-row slot swizzle ----------------
__global__ void k_cvt_x(const float* __restrict__ in, uint32_t* __restrict__ out, int nU){
    int i = blockIdx.x * 256 + threadIdx.x;   // u32 index (2 bf16)
    if (i >= nU) return;
    int r = i >> 6, dw = i & 63;
    uint32_t v = packbf(in[(size_t)i * 2], in[(size_t)i * 2 + 1]);
    int slot = dw >> 2, w = dw & 3;
    out[(size_t)r * 64 + (((slot ^ (r & 7)) << 2) | w)] = v;
}

// ---------------- CSR (only the unsorted half needs building) ----------------
__global__ void k_bound(const int* __restrict__ dstB, int E, int* __restrict__ rows2, int n){
    int v = blockIdx.x * 256 + threadIdx.x;
    if (v > n) return;
    int lo = 0, hi = E;
    while (lo < hi){ int mid = (lo + hi) >> 1; if (dstB[mid] < v) lo = mid + 1; else hi = mid; }
    rows2[v] = lo;
}

__global__ void k_count(const int* __restrict__ dst, int* __restrict__ deg, int ne){
    int i = blockIdx.x * 256 + threadIdx.x;
    if (i < ne) atomicAdd(&deg[dst[i]], 1);
}

__global__ void k_scan1(const int* __restrict__ deg, int* __restrict__ rows,
                        int* __restrict__ bsum, int n){
    __shared__ int lds[256];
    int b = blockIdx.x, tid = threadIdx.x;
    int i0 = b * 1024 + tid * 4;
    int v[4]; int s = 0;
#pragma unroll
    for (int j = 0; j < 4; ++j){ int idx = i0 + j; v[j] = (idx < n) ? deg[idx] : 0; s += v[j]; }
    lds[tid] = s; __syncthreads();
    int acc = s;
    for (int off = 1; off < 256; off <<= 1){
        int add = (tid >= off) ? lds[tid - off] : 0;
        __syncthreads();
        acc += add; lds[tid] = acc;
        __syncthreads();
    }
    int run = acc - s;
#pragma unroll
    for (int j = 0; j < 4; ++j){ int idx = i0 + j; if (idx < n) rows[idx] = run; run += v[j]; }
    if (tid == 255) bsum[b] = acc;
}

__global__ void k_scan2(int* __restrict__ bsum, int nb){
    __shared__ int lds[128];
    int tid = threadIdx.x;
    int v = (tid < nb) ? bsum[tid] : 0;
    lds[tid] = v; __syncthreads();
    int acc = v;
    for (int off = 1; off < 128; off <<= 1){
        int add = (tid >= off) ? lds[tid - off] : 0;
        __syncthreads();
        acc += add; lds[tid] = acc;
        __syncthreads();
    }
    if (tid < nb) bsum[tid] = acc - v;
}

__global__ void k_scan3(int* __restrict__ rows, const int* __restrict__ bsum, int n, int total){
    int i = blockIdx.x * 256 + threadIdx.x;
    if (i < n) rows[i] += bsum[i >> 10];
    if (i == n) rows[n] = total;
}

// XCD-partitioned fill (writes to a col line come from one XCD -> stores merge)
__global__ void k_fillp(const int* __restrict__ src, const int* __restrict__ dst,
                        int* __restrict__ cur, int* __restrict__ col, int ne, int nPerG){
    int g = blockIdx.x & 7;
    int i = (blockIdx.x >> 3) * 256 + threadIdx.x;
    if (i >= ne) return;
    int d = dst[i];
    int lo = g * nPerG;
    if (d >= lo && d < lo + nPerG){
        int p = atomicAdd(&cur[d], 1);
        col[p] = src[i];
    }
}

// ---------------- mean aggregation over swizzled rows ----------------
__global__ __launch_bounds__(256) void k_gather(
    const bf16* __restrict__ curx,
    const int* __restrict__ srcB, const int* __restrict__ rows2,
    const int* __restrict__ colB, const int* __restrict__ rowsB,
    bf16* __restrict__ cout, int n)
{
    int wid = threadIdx.x >> 6, lane = threadIdx.x & 63;
    int v = blockIdx.x * 4 + wid;
    if (v >= n) return;
    int grp = lane >> 3, sl = lane & 7;
    int a0 = rows2[v], a1 = rows2[v + 1];
    int b0 = rowsB[v], b1 = rowsB[v + 1];
    int deg = (a1 - a0) + (b1 - b0);
    float inv = (deg > 0) ? 1.f / (float)deg : 0.f;

    const u32x4* base = (const u32x4*)curx;
    f32x2 acc2[8];
#pragma unroll
    for (int k = 0; k < 8; ++k) acc2[k] = (f32x2){0.f, 0.f};

    for (int j = a0 + grp; j < a1; j += 8){
        int nb = srcB[j];
        int px = nb & 7;
        u32x4 q0 = base[(size_t)nb * 16 + (sl ^ px)];
        u32x4 q1 = base[(size_t)nb * 16 + 8 + (sl ^ px)];
#pragma unroll
        for (int k = 0; k < 4; ++k){
            acc2[k]     += (f32x2){bflo(q0[k]), bfhi(q0[k])};
            acc2[4 + k] += (f32x2){bflo(q1[k]), bfhi(q1[k])};
        }
    }
    for (int j = b0 + grp; j < b1; j += 8){
        int nb = colB[j];
        int px = nb & 7;
        u32x4 q0 = base[(size_t)nb * 16 + (sl ^ px)];
        u32x4 q1 = base[(size_t)nb * 16 + 8 + (sl ^ px)];
#pragma unroll
        for (int k = 0; k < 4; ++k){
            acc2[k]     += (f32x2){bflo(q0[k]), bfhi(q0[k])};
            acc2[4 + k] += (f32x2){bflo(q1[k]), bfhi(q1[k])};
        }
    }
    float acc[16];
#pragma unroll
    for (int k = 0; k < 4; ++k){
        acc[2*k]     = acc2[k].x;     acc[2*k+1]     = acc2[k].y;
        acc[8+2*k]   = acc2[4+k].x;   acc[8+2*k+1]   = acc2[4+k].y;
    }
#pragma unroll
    for (int k = 0; k < 16; ++k){
        acc[k] += __shfl_xor(acc[k], 8);
        acc[k] += __shfl_xor(acc[k], 16);
        acc[k] += __shfl_xor(acc[k], 32);
    }
    if (grp == 0){
        int pv = v & 7;
        u32x4 x0 = base[(size_t)v * 16 + (sl ^ pv)];
        u32x4 x1 = base[(size_t)v * 16 + 8 + (sl ^ pv)];
        u32x4 o0, o1;
#pragma unroll
        for (int k = 0; k < 4; ++k){
            o0[k] = packbf(bflo(x0[k]) + acc[2*k] * inv,   bfhi(x0[k]) + acc[2*k+1] * inv);
            o1[k] = packbf(bflo(x1[k]) + acc[8+2*k] * inv, bfhi(x1[k]) + acc[8+2*k+1] * inv);
        }
        ((u32x4*)cout)[(size_t)v * 16 + (sl ^ pv)]     = o0;
        ((u32x4*)cout)[(size_t)v * 16 + 8 + (sl ^ pv)] = o1;
    }
}

// ---------------- MLP half: 64-row tiles, 48KB LDS, 2 blocks/CU (VGPR<=128) ----------------
// Only 32 weight VGPRs -> fits the 4-waves/SIMD register budget. 3 lgkm-barriers/tile.
#define MT_C0 0u
#define MT_C1 16384u
#define MT_A  32768u
__global__ __launch_bounds__(512, 4) void k_mlp(
    const bf16* __restrict__ cin, bf16* __restrict__ cbn,
    const bf16* __restrict__ W1, const float* __restrict__ b1,
    const bf16* __restrict__ W2, const float* __restrict__ b2,
    const float* __restrict__ gm, const float* __restrict__ bt,
    const float* __restrict__ mu, const float* __restrict__ vr, int nT)
{
    __shared__ __align__(16) char smem[49152];
    int tid = threadIdx.x, wid = tid >> 6, lane = tid & 63;
    int rA = lane & 15, u = lane >> 4, ko = u * 8;
    int c = wid * 16 + rA;

    bf16x8 W1f[4], W2f[4];
#pragma unroll
    for (int kk = 0; kk < 4; ++kk){
        W1f[kk] = ldb8(W1 + (size_t)c * HD + ko + kk * 32);
        W2f[kk] = ldb8(W2 + (size_t)c * HD + ko + kk * 32);
    }
    float b1c = b1[c];
    float bnS = gm[c] * rsqrtf(vr[c] + 1e-5f);
    float bnO = bt[c] - mu[c] * bnS;
    float b2c = b2[c];

    auto gload = [&](const char* g, uint32_t lo){
        __builtin_amdgcn_global_load_lds(
            (const __attribute__((address_space(1))) void*)g,
            (__attribute__((address_space(3))) void*)(smem + lo), 16, 0, 0);
    };
    auto stageC = [&](int t, uint32_t dst){
        const char* g = (const char*)cin + (size_t)t * 16384 + (size_t)lane * 16;
#pragma unroll
        for (int i = 0; i < 2; ++i){
            uint32_t ch = (uint32_t)(wid * 2 + i) * 1024;
            gload(g + ch, dst + ch);
        }
    };

    int t = blockIdx.x;
    int cur = 0;
    if (t < nT) stageC(t, MT_C0);
    asm volatile("s_waitcnt vmcnt(0) lgkmcnt(0)" ::: "memory");
    __builtin_amdgcn_sched_barrier(0);
    __builtin_amdgcn_s_barrier();

    for (; t < nT; t += (int)gridDim.x){
        int tn = t + (int)gridDim.x;
        if (tn < nT) stageC(tn, cur ? MT_C0 : MT_C1);
        uint32_t CB = cur ? MT_C1 : MT_C0;

        // GEMM1 + ReLU: C -> A
#pragma unroll
        for (int m = 0; m < 4; ++m){
            bf16x8 a_[4];
#pragma unroll
            for (int kk = 0; kk < 4; ++kk){
                uint32_t b = (uint32_t)(m * 16 + rA) * 256 + (uint32_t)(u * 16 + kk * 64);
                a_[kk] = *(const bf16x8*)(smem + CB + swz(b));
            }
            f32x4 acc = {0,0,0,0};
#pragma unroll
            for (int kk = 0; kk < 4; ++kk) acc = MFMA(a_[kk], W1f[kk], acc, 0, 0, 0);
#pragma unroll
            for (int j = 0; j < 4; ++j){
                uint32_t r = (uint32_t)(m * 16 + u * 4 + j);
                *(bf16*)(smem + MT_A + swz(r * 256 + (uint32_t)c * 2)) =
                    (bf16)fmaxf(acc[j] + b1c, 0.f);
            }
        }
        asm volatile("s_waitcnt lgkmcnt(0)" ::: "memory");
        __builtin_amdgcn_sched_barrier(0);
        __builtin_amdgcn_s_barrier();

        // GEMM2 + BN: A -> C
#pragma unroll
        for (int m = 0; m < 4; ++m){
            bf16x8 a_[4];
#pragma unroll
            for (int kk = 0; kk < 4; ++kk){
                uint32_t b = (uint32_t)(m * 16 + rA) * 256 + (uint32_t)(u * 16 + kk * 64);
                a_[kk] = *(const bf16x8*)(smem + MT_A + swz(b));
            }
            f32x4 acc = {0,0,0,0};
#pragma unroll
            for (int kk = 0; kk < 4; ++kk) acc = MFMA(a_[kk], W2f[kk], acc, 0, 0, 0);
#pragma unroll
            for (int j = 0; j < 4; ++j){
                uint32_t r = (uint32_t)(m * 16 + u * 4 + j);
                *(bf16*)(smem + CB + swz(r * 256 + (uint32_t)c * 2)) =
                    (bf16)((acc[j] + b2c) * bnS + bnO);
            }
        }
        asm volatile("s_waitcnt lgkmcnt(0)" ::: "memory");
        __builtin_amdgcn_sched_barrier(0);
        __builtin_amdgcn_s_barrier();

        // coalesced copy-out C -> cbn
        {
            char* gout = (char*)cbn + (size_t)t * 16384;
#pragma unroll
            for (int i = 0; i < 2; ++i){
                uint32_t off = (uint32_t)tid * 16 + (uint32_t)i * 8192;
                *(u32x4*)(gout + off) = *(const u32x4*)(smem + CB + off);
            }
        }
        // stage(t+1) loads drained (older); 2 stores may stay in flight
        asm volatile("s_waitcnt vmcnt(2) lgkmcnt(0)" ::: "memory");
        __builtin_amdgcn_sched_barrier(0);
        __builtin_amdgcn_s_barrier();
        cur ^= 1;
    }
}

// ---------------- GRU half: 96-row tiles, all-dbuf 120KB LDS, 2 barriers/tile ------------
// 96 weight VGPRs -> 2 waves/SIMD cap is structural; minimize barriers + prefetch 1 tile.
#define GT_C0 0u
#define GT_C1 24576u
#define GT_H0 49152u
#define GT_H1 73728u
#define GT_O  98304u
__global__ __launch_bounds__(512, 1) void k_gru(
    const bf16* __restrict__ cbn, const bf16* __restrict__ hOld, bf16* __restrict__ hNew,
    const bf16* __restrict__ Wih, const bf16* __restrict__ Whh,
    const float* __restrict__ bih, const float* __restrict__ bhh, int nT)
{
    __shared__ __align__(16) char smem[122880];
    int tid = threadIdx.x, wid = tid >> 6, lane = tid & 63;
    int rA = lane & 15, u = lane >> 4, ko = u * 8;
    int c = wid * 16 + rA;

    bf16x8 Gri[4], Grh[4], Gzi[4], Gzh[4], Gni[4], Gnh[4];
#pragma unroll
    for (int kk = 0; kk < 4; ++kk){
        Gri[kk] = ldb8(Wih + (size_t)c * HD + ko + kk * 32);
        Gzi[kk] = ldb8(Wih + (size_t)(c + 128) * HD + ko + kk * 32);
        Gni[kk] = ldb8(Wih + (size_t)(c + 256) * HD + ko + kk * 32);
        Grh[kk] = ldb8(Whh + (size_t)c * HD + ko + kk * 32);
        Gzh[kk] = ldb8(Whh + (size_t)(c + 128) * HD + ko + kk * 32);
        Gnh[kk] = ldb8(Whh + (size_t)(c + 256) * HD + ko + kk * 32);
    }
    float br = bih[c] + bhh[c], bz = bih[c + 128] + bhh[c + 128];
    float bin = bih[c + 256], bhn = bhh[c + 256];

    auto gload = [&](const char* g, uint32_t lo){
        __builtin_amdgcn_global_load_lds(
            (const __attribute__((address_space(1))) void*)g,
            (__attribute__((address_space(3))) void*)(smem + lo), 16, 0, 0);
    };
    auto stageC = [&](int t, uint32_t dst){
        const char* g = (const char*)cbn + (size_t)t * 24576 + (size_t)lane * 16;
#pragma unroll
        for (int i = 0; i < 3; ++i){
            uint32_t ch = (uint32_t)(wid * 3 + i) * 1024;
            gload(g + ch, dst + ch);
        }
    };
    auto stageH = [&](int t, uint32_t dst){
        const char* g = (const char*)hOld + (size_t)t * 24576 + (size_t)lane * 16;
#pragma unroll
        for (int i = 0; i < 3; ++i){
            uint32_t ch = (uint32_t)(wid * 3 + i) * 1024;
            gload(g + ch, dst + ch);
        }
    };

    int t = blockIdx.x;
    int cur = 0;
    if (t < nT){ stageC(t, GT_C0); stageH(t, GT_H0); }
    asm volatile("s_waitcnt vmcnt(0) lgkmcnt(0)" ::: "memory");
    __builtin_amdgcn_sched_barrier(0);
    __builtin_amdgcn_s_barrier();

    for (; t < nT; t += (int)gridDim.x){
        int tn = t + (int)gridDim.x;
        if (tn < nT){
            stageC(tn, cur ? GT_C0 : GT_C1);
            stageH(tn, cur ? GT_H0 : GT_H1);
        }
        uint32_t CB = cur ? GT_C1 : GT_C0;
        uint32_t HB = cur ? GT_H1 : GT_H0;

#pragma unroll
        for (int m = 0; m < 6; ++m){
            bf16x8 ac_[4], ah_[4];
#pragma unroll
            for (int kk = 0; kk < 4; ++kk){
                uint32_t b = (uint32_t)(m * 16 + rA) * 256 + (uint32_t)(u * 16 + kk * 64);
                ac_[kk] = *(const bf16x8*)(smem + CB + swz(b));
                ah_[kk] = *(const bf16x8*)(smem + HB + swz(b));
            }
            f32x4 rr = {0,0,0,0}, zz = {0,0,0,0}, gi = {0,0,0,0}, gh = {0,0,0,0};
#pragma unroll
            for (int kk = 0; kk < 4; ++kk){
                rr = MFMA(ac_[kk], Gri[kk], rr, 0, 0, 0);
                rr = MFMA(ah_[kk], Grh[kk], rr, 0, 0, 0);
                zz = MFMA(ac_[kk], Gzi[kk], zz, 0, 0, 0);
                zz = MFMA(ah_[kk], Gzh[kk], zz, 0, 0, 0);
                gi = MFMA(ac_[kk], Gni[kk], gi, 0, 0, 0);
                gh = MFMA(ah_[kk], Gnh[kk], gh, 0, 0, 0);
            }
#pragma unroll
            for (int j = 0; j < 4; ++j){
                uint32_t r = (uint32_t)(m * 16 + u * 4 + j);
                uint32_t inner = swz(r * 256 + (uint32_t)c * 2);
                float hold = (float)*(const bf16*)(smem + HB + inner);
                float rg = sigm(rr[j] + br);
                float zg = sigm(zz[j] + bz);
                float ng = tanh_fast(gi[j] + bin + rg * (gh[j] + bhn));
                *(bf16*)(smem + GT_O + inner) = (bf16)((1.f - zg) * ng + zg * hold);
            }
        }
        asm volatile("s_waitcnt lgkmcnt(0)" ::: "memory");
        __builtin_amdgcn_sched_barrier(0);
        __builtin_amdgcn_s_barrier();

        // coalesced copy-out OUT -> hNew
        {
            char* hNb = (char*)hNew + (size_t)t * 24576;
#pragma unroll
            for (int i = 0; i < 3; ++i){
                uint32_t off = (uint32_t)tid * 16 + (uint32_t)i * 8192;
                *(u32x4*)(hNb + off) = *(const u32x4*)(smem + GT_O + off);
            }
        }
        // 6 stage loads (older) drained; 3 stores may stay in flight
        asm volatile("s_waitcnt vmcnt(3) lgkmcnt(0)" ::: "memory");
        __builtin_amdgcn_sched_barrier(0);
        __builtin_amdgcn_s_barrier();
        cur ^= 1;
    }
}

// ---------------- final MLP: 128 -> 128 (ReLU) -> 64, f32 out ----------------
__global__ __launch_bounds__(256) void k_final(
    const bf16* __restrict__ hin, const bf16* __restrict__ W1, const float* __restrict__ b1,
    const bf16* __restrict__ W2, const float* __restrict__ b2,
    float* __restrict__ out, int nTiles)
{
    __shared__ bf16 lds[NTPB][16][LDP];
    int wid = threadIdx.x >> 6, lane = threadIdx.x & 63;
    int tile = blockIdx.x * NTPB + wid;
    if (tile >= nTiles) return;
    int r0 = tile * 16;
    int rA = lane & 15, u = lane >> 4, ko = u * 8;

    bf16x8 a[4];
    const char* hb = (const char*)hin;
    uint32_t b0 = (uint32_t)(r0 + rA) * 256 + (uint32_t)(u * 16);
#pragma unroll
    for (int kk = 0; kk < 4; ++kk) a[kk] = *(const bf16x8*)(hb + swz(b0 + (uint32_t)kk * 64));

#pragma unroll
    for (int t = 0; t < 8; ++t){
        f32x4 acc = {0.f, 0.f, 0.f, 0.f};
        int c = t * 16 + rA;
        const bf16* bp = W1 + (size_t)c * HD + ko;
#pragma unroll
        for (int kk = 0; kk < 4; ++kk)
            acc = MFMA(a[kk], ldb8(bp + kk * 32), acc, 0, 0, 0);
        float bias = b1[c];
#pragma unroll
        for (int j = 0; j < 4; ++j){
            float v = fmaxf(acc[j] + bias, 0.f);
            lds[wid][u * 4 + j][c] = (bf16)v;
        }
    }
    __threadfence_block();
    bf16x8 a2[4];
    const bf16* lp = &lds[wid][rA][ko];
#pragma unroll
    for (int kk = 0; kk < 4; ++kk) a2[kk] = ldb8(lp + kk * 32);

#pragma unroll
    for (int t = 0; t < 4; ++t){
        f32x4 acc = {0.f, 0.f, 0.f, 0.f};
        int c = t * 16 + rA;
        const bf16* bp = W2 + (size_t)c * HD + ko;
#pragma unroll
        for (int kk = 0; kk < 4; ++kk)
            acc = MFMA(a2[kk], ldb8(bp + kk * 32), acc, 0, 0, 0);
        float bias = b2[c];
#pragma unroll
        for (int j = 0; j < 4; ++j)
            out[(size_t)(r0 + u * 4 + j) * 64 + c] = acc[j] + bias;
    }
}

extern "C" void kernel_launch(void* const* d_in, const int* in_sizes, int n_in,
                              void* d_out, int out_size, void* d_ws, size_t ws_size,
                              hipStream_t stream)
{
    const float* x    = (const float*)d_in[0];
    const int*   src  = (const int*)d_in[1];
    const int*   dst  = (const int*)d_in[2];
    const float* lW1  = (const float*)d_in[3];
    const float* lb1  = (const float*)d_in[4];
    const float* lW2  = (const float*)d_in[5];
    const float* lb2  = (const float*)d_in[6];
    const float* gmm  = (const float*)d_in[7];
    const float* bta  = (const float*)d_in[8];
    const float* mun  = (const float*)d_in[9];
    const float* vrr  = (const float*)d_in[10];
    const float* Wih  = (const float*)d_in[11];
    const float* Whh  = (const float*)d_in[12];
    const float* bih  = (const float*)d_in[13];
    const float* bhh  = (const float*)d_in[14];
    const float* fW1  = (const float*)d_in[15];
    const float* fb1  = (const float*)d_in[16];
    const float* fW2  = (const float*)d_in[17];
    const float* fb2  = (const float*)d_in[18];

    int n  = in_sizes[0] / HD;
    int ne = in_sizes[1];
    int E  = ne / 2;                    // dst[E:2E) is sorted
    int L  = in_sizes[3] / (HD * HD);
    int nPad = (n + 191) / 192 * 192;   // multiple of 64 AND 96

    char* w = (char*)d_ws;
    auto alloc = [&](size_t bytes) -> char* {
        char* p = w; w += (bytes + 255) & ~(size_t)255; return p;
    };
    bf16* xbf  = (bf16*)alloc((size_t)nPad * HD * 2);
    bf16* hA   = (bf16*)alloc((size_t)nPad * HD * 2);
    bf16* hB   = (bf16*)alloc((size_t)nPad * HD * 2);
    bf16* cin  = (bf16*)alloc((size_t)nPad * HD * 2);
    bf16* cbn  = (bf16*)alloc((size_t)nPad * HD * 2);
    bf16* W1b  = (bf16*)alloc((size_t)L * HD * HD * 2);
    bf16* W2b  = (bf16*)alloc((size_t)L * HD * HD * 2);
    bf16* Wib  = (bf16*)alloc((size_t)3 * HD * HD * 2);
    bf16* Whb  = (bf16*)alloc((size_t)3 * HD * HD * 2);
    bf16* fW1b = (bf16*)alloc((size_t)HD * HD * 2);
    bf16* fW2b = (bf16*)alloc((size_t)64 * HD * 2);
    int*  degB = (int*)alloc((size_t)n * 4);
    int*  rowsB= (int*)alloc((size_t)(n + 1) * 4);
    int*  rows2= (int*)alloc((size_t)(n + 1) * 4);
    int*  bsum = (int*)alloc(512);
    int*  curB = (int*)alloc((size_t)n * 4);
    int*  colB = (int*)alloc((size_t)E * 4);

    auto cvt = [&](const float* i, bf16* o, int cnt){
        k_cvt<<<(cnt + 255) / 256, 256, 0, stream>>>(i, o, cnt);
    };
    int nU = n * 64;
    k_cvt_x<<<(nU + 255) / 256, 256, 0, stream>>>(x, (uint32_t*)xbf, nU);
    cvt(lW1, W1b,  L * HD * HD);
    cvt(lW2, W2b,  L * HD * HD);
    cvt(Wih, Wib,  3 * HD * HD);
    cvt(Whh, Whb,  3 * HD * HD);
    cvt(fW1, fW1b, HD * HD);
    cvt(fW2, fW2b, 64 * HD);

    hipMemsetAsync(degB, 0, (size_t)n * 4, stream);
    hipMemsetAsync(hA, 0, (size_t)nPad * HD * 2, stream);

    k_bound<<<(n + 1 + 255) / 256, 256, 0, stream>>>(dst + E, E, rows2, n);
    k_count<<<(E + 255) / 256, 256, 0, stream>>>(dst, degB, E);
    int nb = (n + 1023) / 1024;
    k_scan1<<<nb, 256, 0, stream>>>(degB, rowsB, bsum, n);
    k_scan2<<<1, 128, 0, stream>>>(bsum, nb);
    k_scan3<<<(n + 1 + 255) / 256, 256, 0, stream>>>(rowsB, bsum, n, E);
    hipMemcpyAsync(curB, rowsB, (size_t)n * 4, hipMemcpyDeviceToDevice, stream);
    int nPerG = (n + 7) / 8;
    k_fillp<<<8 * ((E + 255) / 256), 256, 0, stream>>>(src, dst, curB, colB, E, nPerG);

    int nT64 = nPad / 64;
    int nT96 = nPad / 96;
    int gM = (nT64 < 512) ? nT64 : 512;   // 2 blocks/CU
    int gG = (nT96 < 256) ? nT96 : 256;   // 1 block/CU
    int nT16 = (n + 15) / 16;
    int gF = (nT16 + NTPB - 1) / NTPB;

    const bf16* curp = xbf;
    for (int l = 0; l < L; ++l){
        k_gather<<<(n + 3) / 4, 256, 0, stream>>>(curp, src + E, rows2, colB, rowsB, cin, n);
        k_mlp<<<gM, 512, 0, stream>>>(cin, cbn,
            W1b + (size_t)l * HD * HD, lb1 + l * HD,
            W2b + (size_t)l * HD * HD, lb2 + l * HD,
            gmm + l * HD, bta + l * HD, mun + l * HD, vrr + l * HD, nT64);
        k_gru<<<gG, 512, 0, stream>>>(cbn, hA, hB, Wib, Whb, bih, bhh, nT96);
        bf16* tmp = hA; hA = hB; hB = tmp;
        curp = hA;
    }
    k_final<<<gF, 256, 0, stream>>>(hA, fW1b, fb1, fW2b, fb2, (float*)d_out, nT16);
}

// Round 14
// 729.177 us; speedup vs baseline: 1.6114x; 1.0259x over previous
//
#include <hip/hip_runtime.h>
#include <hip/hip_bf16.h>
#include <stdint.h>

typedef __bf16 bf16;
typedef __bf16 bf16x8 __attribute__((ext_vector_type(8)));
typedef float f32x4 __attribute__((ext_vector_type(4)));
typedef float f32x2 __attribute__((ext_vector_type(2)));
typedef uint32_t u32x4 __attribute__((ext_vector_type(4)));

#define HD 128
#define LDP (HD + 8)
#define NTPB 4
#define MFMA __builtin_amdgcn_mfma_f32_16x16x32_bf16

__device__ inline float bflo(uint32_t u){ return __uint_as_float(u << 16); }
__device__ inline float bfhi(uint32_t u){ return __uint_as_float(u & 0xffff0000u); }
__device__ inline uint32_t packbf(float a, float b){
    bf16 x = (bf16)a, y = (bf16)b;
    uint16_t ux = __builtin_bit_cast(uint16_t, x), uy = __builtin_bit_cast(uint16_t, y);
    return (uint32_t)ux | ((uint32_t)uy << 16);
}
__device__ inline bf16x8 ldb8(const bf16* p){ return *(const bf16x8*)p; }
__device__ inline float sigm(float x){ return 1.f / (1.f + __expf(-x)); }
__device__ inline float tanh_fast(float x){ float t = __expf(-2.f * x); return (1.f - t) / (1.f + t); }
// 16B-slot swizzle within a 256B row: slot ^= row&7. Self-inverse.
__device__ inline uint32_t swz(uint32_t b){ return b ^ (((b >> 8) & 7u) << 4); }

// ---------------- fused weight conversion (6 segments, 1 launch) ----------------
struct CvtSeg { const float* s; bf16* d; };
struct Cvt6 { CvtSeg seg[6]; int cum[7]; };
__global__ void k_cvt6(Cvt6 a, int total){
    int i = blockIdx.x * 256 + threadIdx.x;
    if (i >= total) return;
#pragma unroll
    for (int s = 0; s < 6; ++s){
        if (i >= a.cum[s] && i < a.cum[s + 1]){
            int k = i - a.cum[s];
            a.seg[s].d[k] = (bf16)a.seg[s].s[k];
        }
    }
}

// ---------------- x conversion with per-row slot swizzle ----------------
__global__ void k_cvt_x(const float* __restrict__ in, uint32_t* __restrict__ out, int nU){
    int i = blockIdx.x * 256 + threadIdx.x;   // u32 index (2 bf16)
    if (i >= nU) return;
    int r = i >> 6, dw = i & 63;
    uint32_t v = packbf(in[(size_t)i * 2], in[(size_t)i * 2 + 1]);
    int slot = dw >> 2, w = dw & 3;
    out[(size_t)r * 64 + (((slot ^ (r & 7)) << 2) | w)] = v;
}

// ---------------- CSR: fused bound (sorted half) + count (unsorted half) ----------------
__global__ void k_bc(const int* __restrict__ dstB, int E, int* __restrict__ rows2, int n,
                     const int* __restrict__ dst, int* __restrict__ deg, int nbB){
    if ((int)blockIdx.x < nbB){
        int v = blockIdx.x * 256 + threadIdx.x;
        if (v > n) return;
        int lo = 0, hi = E;
        while (lo < hi){ int mid = (lo + hi) >> 1; if (dstB[mid] < v) lo = mid + 1; else hi = mid; }
        rows2[v] = lo;
    } else {
        int i = (blockIdx.x - nbB) * 256 + threadIdx.x;
        if (i < E) atomicAdd(&deg[dst[i]], 1);
    }
}

__global__ void k_scan1(const int* __restrict__ deg, int* __restrict__ rows,
                        int* __restrict__ bsum, int n){
    __shared__ int lds[256];
    int b = blockIdx.x, tid = threadIdx.x;
    int i0 = b * 1024 + tid * 4;
    int v[4]; int s = 0;
#pragma unroll
    for (int j = 0; j < 4; ++j){ int idx = i0 + j; v[j] = (idx < n) ? deg[idx] : 0; s += v[j]; }
    lds[tid] = s; __syncthreads();
    int acc = s;
    for (int off = 1; off < 256; off <<= 1){
        int add = (tid >= off) ? lds[tid - off] : 0;
        __syncthreads();
        acc += add; lds[tid] = acc;
        __syncthreads();
    }
    int run = acc - s;
#pragma unroll
    for (int j = 0; j < 4; ++j){ int idx = i0 + j; if (idx < n) rows[idx] = run; run += v[j]; }
    if (tid == 255) bsum[b] = acc;
}

__global__ void k_scan2(int* __restrict__ bsum, int nb){
    __shared__ int lds[128];
    int tid = threadIdx.x;
    int v = (tid < nb) ? bsum[tid] : 0;
    lds[tid] = v; __syncthreads();
    int acc = v;
    for (int off = 1; off < 128; off <<= 1){
        int add = (tid >= off) ? lds[tid - off] : 0;
        __syncthreads();
        acc += add; lds[tid] = acc;
        __syncthreads();
    }
    if (tid < nb) bsum[tid] = acc - v;
}

// also seeds curB (folds the old hipMemcpyAsync)
__global__ void k_scan3(int* __restrict__ rows, const int* __restrict__ bsum,
                        int* __restrict__ curB, int n, int total){
    int i = blockIdx.x * 256 + threadIdx.x;
    if (i < n){ int r = rows[i] + bsum[i >> 10]; rows[i] = r; curB[i] = r; }
    if (i == n) rows[n] = total;
}

// XCD-partitioned fill (writes to a col line come from one XCD -> stores merge)
__global__ void k_fillp(const int* __restrict__ src, const int* __restrict__ dst,
                        int* __restrict__ cur, int* __restrict__ col, int ne, int nPerG){
    int g = blockIdx.x & 7;
    int i = (blockIdx.x >> 3) * 256 + threadIdx.x;
    if (i >= ne) return;
    int d = dst[i];
    int lo = g * nPerG;
    if (d >= lo && d < lo + nPerG){
        int p = atomicAdd(&cur[d], 1);
        col[p] = src[i];
    }
}

// ---------------- mean aggregation: unified stream, 2-deep software pipeline ----------
// Issue iteration p+8's index + row loads BEFORE consuming iteration p's registers:
// breaks the per-iter serial chain (idx load -> row load -> unpack) and doubles
// vmem-in-flight per wave.
__global__ __launch_bounds__(256) void k_gather(
    const bf16* __restrict__ curx,
    const int* __restrict__ srcB, const int* __restrict__ rows2,
    const int* __restrict__ colB, const int* __restrict__ rowsB,
    bf16* __restrict__ cout, int n)
{
    int wid = threadIdx.x >> 6, lane = threadIdx.x & 63;
    int v = blockIdx.x * 4 + wid;
    if (v >= n) return;
    int grp = lane >> 3, sl = lane & 7;
    int a0 = rows2[v], a1 = rows2[v + 1];
    int b0 = rowsB[v], b1 = rowsB[v + 1];
    int lenA = a1 - a0;
    int tot  = lenA + (b1 - b0);
    float inv = (tot > 0) ? 1.f / (float)tot : 0.f;

    const u32x4* base = (const u32x4*)curx;
    f32x2 acc2[8];
#pragma unroll
    for (int k = 0; k < 8; ++k) acc2[k] = (f32x2){0.f, 0.f};

    auto nbidx = [&](int p)->int {
        return (p < lenA) ? srcB[a0 + p] : colB[b0 + p - lenA];
    };

    u32x4 qa0, qa1;
    int p = grp;
    if (p < tot){
        int nb = nbidx(p); int px = nb & 7;
        qa0 = base[(size_t)nb * 16 + (sl ^ px)];
        qa1 = base[(size_t)nb * 16 + 8 + (sl ^ px)];
    }
    while (p < tot){
        int pn = p + 8;
        u32x4 qb0, qb1;
        if (pn < tot){
            int nb = nbidx(pn); int px = nb & 7;
            qb0 = base[(size_t)nb * 16 + (sl ^ px)];
            qb1 = base[(size_t)nb * 16 + 8 + (sl ^ px)];
        }
#pragma unroll
        for (int k = 0; k < 4; ++k){
            acc2[k]     += (f32x2){bflo(qa0[k]), bfhi(qa0[k])};   // v_pk_add_f32
            acc2[4 + k] += (f32x2){bflo(qa1[k]), bfhi(qa1[k])};
        }
        qa0 = qb0; qa1 = qb1;
        p = pn;
    }

    float acc[16];
#pragma unroll
    for (int k = 0; k < 4; ++k){
        acc[2*k]     = acc2[k].x;     acc[2*k+1]     = acc2[k].y;
        acc[8+2*k]   = acc2[4+k].x;   acc[8+2*k+1]   = acc2[4+k].y;
    }
#pragma unroll
    for (int k = 0; k < 16; ++k){
        acc[k] += __shfl_xor(acc[k], 8);
        acc[k] += __shfl_xor(acc[k], 16);
        acc[k] += __shfl_xor(acc[k], 32);
    }
    if (grp == 0){
        int pv = v & 7;
        u32x4 x0 = base[(size_t)v * 16 + (sl ^ pv)];
        u32x4 x1 = base[(size_t)v * 16 + 8 + (sl ^ pv)];
        u32x4 o0, o1;
#pragma unroll
        for (int k = 0; k < 4; ++k){
            o0[k] = packbf(bflo(x0[k]) + acc[2*k] * inv,   bfhi(x0[k]) + acc[2*k+1] * inv);
            o1[k] = packbf(bflo(x1[k]) + acc[8+2*k] * inv, bfhi(x1[k]) + acc[8+2*k+1] * inv);
        }
        ((u32x4*)cout)[(size_t)v * 16 + (sl ^ pv)]     = o0;
        ((u32x4*)cout)[(size_t)v * 16 + 8 + (sl ^ pv)] = o1;
    }
}

// ---------------- MLP half: 64-row tiles, 48KB LDS, 2 blocks/CU (VGPR<=128) ----------------
#define MT_C0 0u
#define MT_C1 16384u
#define MT_A  32768u
__global__ __launch_bounds__(512, 4) void k_mlp(
    const bf16* __restrict__ cin, bf16* __restrict__ cbn,
    const bf16* __restrict__ W1, const float* __restrict__ b1,
    const bf16* __restrict__ W2, const float* __restrict__ b2,
    const float* __restrict__ gm, const float* __restrict__ bt,
    const float* __restrict__ mu, const float* __restrict__ vr, int nT)
{
    __shared__ __align__(16) char smem[49152];
    int tid = threadIdx.x, wid = tid >> 6, lane = tid & 63;
    int rA = lane & 15, u = lane >> 4, ko = u * 8;
    int c = wid * 16 + rA;

    bf16x8 W1f[4], W2f[4];
#pragma unroll
    for (int kk = 0; kk < 4; ++kk){
        W1f[kk] = ldb8(W1 + (size_t)c * HD + ko + kk * 32);
        W2f[kk] = ldb8(W2 + (size_t)c * HD + ko + kk * 32);
    }
    float b1c = b1[c];
    float bnS = gm[c] * rsqrtf(vr[c] + 1e-5f);
    float bnO = bt[c] - mu[c] * bnS;
    float b2c = b2[c];

    auto gload = [&](const char* g, uint32_t lo){
        __builtin_amdgcn_global_load_lds(
            (const __attribute__((address_space(1))) void*)g,
            (__attribute__((address_space(3))) void*)(smem + lo), 16, 0, 0);
    };
    auto stageC = [&](int t, uint32_t dst){
        const char* g = (const char*)cin + (size_t)t * 16384 + (size_t)lane * 16;
#pragma unroll
        for (int i = 0; i < 2; ++i){
            uint32_t ch = (uint32_t)(wid * 2 + i) * 1024;
            gload(g + ch, dst + ch);
        }
    };

    int t = blockIdx.x;
    int cur = 0;
    if (t < nT) stageC(t, MT_C0);
    asm volatile("s_waitcnt vmcnt(0) lgkmcnt(0)" ::: "memory");
    __builtin_amdgcn_sched_barrier(0);
    __builtin_amdgcn_s_barrier();

    for (; t < nT; t += (int)gridDim.x){
        int tn = t + (int)gridDim.x;
        if (tn < nT) stageC(tn, cur ? MT_C0 : MT_C1);
        uint32_t CB = cur ? MT_C1 : MT_C0;

        // GEMM1 + ReLU: C -> A
#pragma unroll
        for (int m = 0; m < 4; ++m){
            bf16x8 a_[4];
#pragma unroll
            for (int kk = 0; kk < 4; ++kk){
                uint32_t b = (uint32_t)(m * 16 + rA) * 256 + (uint32_t)(u * 16 + kk * 64);
                a_[kk] = *(const bf16x8*)(smem + CB + swz(b));
            }
            f32x4 acc = {0,0,0,0};
#pragma unroll
            for (int kk = 0; kk < 4; ++kk) acc = MFMA(a_[kk], W1f[kk], acc, 0, 0, 0);
#pragma unroll
            for (int j = 0; j < 4; ++j){
                uint32_t r = (uint32_t)(m * 16 + u * 4 + j);
                *(bf16*)(smem + MT_A + swz(r * 256 + (uint32_t)c * 2)) =
                    (bf16)fmaxf(acc[j] + b1c, 0.f);
            }
        }
        asm volatile("s_waitcnt lgkmcnt(0)" ::: "memory");
        __builtin_amdgcn_sched_barrier(0);
        __builtin_amdgcn_s_barrier();

        // GEMM2 + BN: A -> C
#pragma unroll
        for (int m = 0; m < 4; ++m){
            bf16x8 a_[4];
#pragma unroll
            for (int kk = 0; kk < 4; ++kk){
                uint32_t b = (uint32_t)(m * 16 + rA) * 256 + (uint32_t)(u * 16 + kk * 64);
                a_[kk] = *(const bf16x8*)(smem + MT_A + swz(b));
            }
            f32x4 acc = {0,0,0,0};
#pragma unroll
            for (int kk = 0; kk < 4; ++kk) acc = MFMA(a_[kk], W2f[kk], acc, 0, 0, 0);
#pragma unroll
            for (int j = 0; j < 4; ++j){
                uint32_t r = (uint32_t)(m * 16 + u * 4 + j);
                *(bf16*)(smem + CB + swz(r * 256 + (uint32_t)c * 2)) =
                    (bf16)((acc[j] + b2c) * bnS + bnO);
            }
        }
        asm volatile("s_waitcnt lgkmcnt(0)" ::: "memory");
        __builtin_amdgcn_sched_barrier(0);
        __builtin_amdgcn_s_barrier();

        // coalesced copy-out C -> cbn
        {
            char* gout = (char*)cbn + (size_t)t * 16384;
#pragma unroll
            for (int i = 0; i < 2; ++i){
                uint32_t off = (uint32_t)tid * 16 + (uint32_t)i * 8192;
                *(u32x4*)(gout + off) = *(const u32x4*)(smem + CB + off);
            }
        }
        asm volatile("s_waitcnt vmcnt(2) lgkmcnt(0)" ::: "memory");
        __builtin_amdgcn_sched_barrier(0);
        __builtin_amdgcn_s_barrier();
        cur ^= 1;
    }
}

// ---------------- GRU half: 96-row tiles, all-dbuf 120KB LDS, 2 barriers/tile ------------
#define GT_C0 0u
#define GT_C1 24576u
#define GT_H0 49152u
#define GT_H1 73728u
#define GT_O  98304u
__global__ __launch_bounds__(512, 1) void k_gru(
    const bf16* __restrict__ cbn, const bf16* __restrict__ hOld, bf16* __restrict__ hNew,
    const bf16* __restrict__ Wih, const bf16* __restrict__ Whh,
    const float* __restrict__ bih, const float* __restrict__ bhh, int nT)
{
    __shared__ __align__(16) char smem[122880];
    int tid = threadIdx.x, wid = tid >> 6, lane = tid & 63;
    int rA = lane & 15, u = lane >> 4, ko = u * 8;
    int c = wid * 16 + rA;

    bf16x8 Gri[4], Grh[4], Gzi[4], Gzh[4], Gni[4], Gnh[4];
#pragma unroll
    for (int kk = 0; kk < 4; ++kk){
        Gri[kk] = ldb8(Wih + (size_t)c * HD + ko + kk * 32);
        Gzi[kk] = ldb8(Wih + (size_t)(c + 128) * HD + ko + kk * 32);
        Gni[kk] = ldb8(Wih + (size_t)(c + 256) * HD + ko + kk * 32);
        Grh[kk] = ldb8(Whh + (size_t)c * HD + ko + kk * 32);
        Gzh[kk] = ldb8(Whh + (size_t)(c + 128) * HD + ko + kk * 32);
        Gnh[kk] = ldb8(Whh + (size_t)(c + 256) * HD + ko + kk * 32);
    }
    float br = bih[c] + bhh[c], bz = bih[c + 128] + bhh[c + 128];
    float bin = bih[c + 256], bhn = bhh[c + 256];

    auto gload = [&](const char* g, uint32_t lo){
        __builtin_amdgcn_global_load_lds(
            (const __attribute__((address_space(1))) void*)g,
            (__attribute__((address_space(3))) void*)(smem + lo), 16, 0, 0);
    };
    auto stageC = [&](int t, uint32_t dst){
        const char* g = (const char*)cbn + (size_t)t * 24576 + (size_t)lane * 16;
#pragma unroll
        for (int i = 0; i < 3; ++i){
            uint32_t ch = (uint32_t)(wid * 3 + i) * 1024;
            gload(g + ch, dst + ch);
        }
    };
    auto stageH = [&](int t, uint32_t dst){
        const char* g = (const char*)hOld + (size_t)t * 24576 + (size_t)lane * 16;
#pragma unroll
        for (int i = 0; i < 3; ++i){
            uint32_t ch = (uint32_t)(wid * 3 + i) * 1024;
            gload(g + ch, dst + ch);
        }
    };

    int t = blockIdx.x;
    int cur = 0;
    if (t < nT){ stageC(t, GT_C0); stageH(t, GT_H0); }
    asm volatile("s_waitcnt vmcnt(0) lgkmcnt(0)" ::: "memory");
    __builtin_amdgcn_sched_barrier(0);
    __builtin_amdgcn_s_barrier();

    for (; t < nT; t += (int)gridDim.x){
        int tn = t + (int)gridDim.x;
        if (tn < nT){
            stageC(tn, cur ? GT_C0 : GT_C1);
            stageH(tn, cur ? GT_H0 : GT_H1);
        }
        uint32_t CB = cur ? GT_C1 : GT_C0;
        uint32_t HB = cur ? GT_H1 : GT_H0;

#pragma unroll
        for (int m = 0; m < 6; ++m){
            bf16x8 ac_[4], ah_[4];
#pragma unroll
            for (int kk = 0; kk < 4; ++kk){
                uint32_t b = (uint32_t)(m * 16 + rA) * 256 + (uint32_t)(u * 16 + kk * 64);
                ac_[kk] = *(const bf16x8*)(smem + CB + swz(b));
                ah_[kk] = *(const bf16x8*)(smem + HB + swz(b));
            }
            f32x4 rr = {0,0,0,0}, zz = {0,0,0,0}, gi = {0,0,0,0}, gh = {0,0,0,0};
#pragma unroll
            for (int kk = 0; kk < 4; ++kk){
                rr = MFMA(ac_[kk], Gri[kk], rr, 0, 0, 0);
                rr = MFMA(ah_[kk], Grh[kk], rr, 0, 0, 0);
                zz = MFMA(ac_[kk], Gzi[kk], zz, 0, 0, 0);
                zz = MFMA(ah_[kk], Gzh[kk], zz, 0, 0, 0);
                gi = MFMA(ac_[kk], Gni[kk], gi, 0, 0, 0);
                gh = MFMA(ah_[kk], Gnh[kk], gh, 0, 0, 0);
            }
#pragma unroll
            for (int j = 0; j < 4; ++j){
                uint32_t r = (uint32_t)(m * 16 + u * 4 + j);
                uint32_t inner = swz(r * 256 + (uint32_t)c * 2);
                float hold = (float)*(const bf16*)(smem + HB + inner);
                float rg = sigm(rr[j] + br);
                float zg = sigm(zz[j] + bz);
                float ng = tanh_fast(gi[j] + bin + rg * (gh[j] + bhn));
                *(bf16*)(smem + GT_O + inner) = (bf16)((1.f - zg) * ng + zg * hold);
            }
        }
        asm volatile("s_waitcnt lgkmcnt(0)" ::: "memory");
        __builtin_amdgcn_sched_barrier(0);
        __builtin_amdgcn_s_barrier();

        // coalesced copy-out OUT -> hNew
        {
            char* hNb = (char*)hNew + (size_t)t * 24576;
#pragma unroll
            for (int i = 0; i < 3; ++i){
                uint32_t off = (uint32_t)tid * 16 + (uint32_t)i * 8192;
                *(u32x4*)(hNb + off) = *(const u32x4*)(smem + GT_O + off);
            }
        }
        asm volatile("s_waitcnt vmcnt(3) lgkmcnt(0)" ::: "memory");
        __builtin_amdgcn_sched_barrier(0);
        __builtin_amdgcn_s_barrier();
        cur ^= 1;
    }
}

// ---------------- final MLP: 128 -> 128 (ReLU) -> 64, f32 out ----------------
__global__ __launch_bounds__(256) void k_final(
    const bf16* __restrict__ hin, const bf16* __restrict__ W1, const float* __restrict__ b1,
    const bf16* __restrict__ W2, const float* __restrict__ b2,
    float* __restrict__ out, int nTiles)
{
    __shared__ bf16 lds[NTPB][16][LDP];
    int wid = threadIdx.x >> 6, lane = threadIdx.x & 63;
    int tile = blockIdx.x * NTPB + wid;
    if (tile >= nTiles) return;
    int r0 = tile * 16;
    int rA = lane & 15, u = lane >> 4, ko = u * 8;

    bf16x8 a[4];
    const char* hb = (const char*)hin;
    uint32_t b0 = (uint32_t)(r0 + rA) * 256 + (uint32_t)(u * 16);
#pragma unroll
    for (int kk = 0; kk < 4; ++kk) a[kk] = *(const bf16x8*)(hb + swz(b0 + (uint32_t)kk * 64));

#pragma unroll
    for (int t = 0; t < 8; ++t){
        f32x4 acc = {0.f, 0.f, 0.f, 0.f};
        int c = t * 16 + rA;
        const bf16* bp = W1 + (size_t)c * HD + ko;
#pragma unroll
        for (int kk = 0; kk < 4; ++kk)
            acc = MFMA(a[kk], ldb8(bp + kk * 32), acc, 0, 0, 0);
        float bias = b1[c];
#pragma unroll
        for (int j = 0; j < 4; ++j){
            float v = fmaxf(acc[j] + bias, 0.f);
            lds[wid][u * 4 + j][c] = (bf16)v;
        }
    }
    __threadfence_block();
    bf16x8 a2[4];
    const bf16* lp = &lds[wid][rA][ko];
#pragma unroll
    for (int kk = 0; kk < 4; ++kk) a2[kk] = ldb8(lp + kk * 32);

#pragma unroll
    for (int t = 0; t < 4; ++t){
        f32x4 acc = {0.f, 0.f, 0.f, 0.f};
        int c = t * 16 + rA;
        const bf16* bp = W2 + (size_t)c * HD + ko;
#pragma unroll
        for (int kk = 0; kk < 4; ++kk)
            acc = MFMA(a2[kk], ldb8(bp + kk * 32), acc, 0, 0, 0);
        float bias = b2[c];
#pragma unroll
        for (int j = 0; j < 4; ++j)
            out[(size_t)(r0 + u * 4 + j) * 64 + c] = acc[j] + bias;
    }
}

extern "C" void kernel_launch(void* const* d_in, const int* in_sizes, int n_in,
                              void* d_out, int out_size, void* d_ws, size_t ws_size,
                              hipStream_t stream)
{
    const float* x    = (const float*)d_in[0];
    const int*   src  = (const int*)d_in[1];
    const int*   dst  = (const int*)d_in[2];
    const float* lW1  = (const float*)d_in[3];
    const float* lb1  = (const float*)d_in[4];
    const float* lW2  = (const float*)d_in[5];
    const float* lb2  = (const float*)d_in[6];
    const float* gmm  = (const float*)d_in[7];
    const float* bta  = (const float*)d_in[8];
    const float* mun  = (const float*)d_in[9];
    const float* vrr  = (const float*)d_in[10];
    const float* Wih  = (const float*)d_in[11];
    const float* Whh  = (const float*)d_in[12];
    const float* bih  = (const float*)d_in[13];
    const float* bhh  = (const float*)d_in[14];
    const float* fW1  = (const float*)d_in[15];
    const float* fb1  = (const float*)d_in[16];
    const float* fW2  = (const float*)d_in[17];
    const float* fb2  = (const float*)d_in[18];

    int n  = in_sizes[0] / HD;
    int ne = in_sizes[1];
    int E  = ne / 2;                    // dst[E:2E) is sorted
    int L  = in_sizes[3] / (HD * HD);
    int nPad = (n + 191) / 192 * 192;   // multiple of 64 AND 96

    char* w = (char*)d_ws;
    auto alloc = [&](size_t bytes) -> char* {
        char* p = w; w += (bytes + 255) & ~(size_t)255; return p;
    };
    bf16* xbf  = (bf16*)alloc((size_t)nPad * HD * 2);
    bf16* hA   = (bf16*)alloc((size_t)nPad * HD * 2);
    bf16* hB   = (bf16*)alloc((size_t)nPad * HD * 2);
    bf16* cin  = (bf16*)alloc((size_t)nPad * HD * 2);
    bf16* cbn  = (bf16*)alloc((size_t)nPad * HD * 2);
    bf16* W1b  = (bf16*)alloc((size_t)L * HD * HD * 2);
    bf16* W2b  = (bf16*)alloc((size_t)L * HD * HD * 2);
    bf16* Wib  = (bf16*)alloc((size_t)3 * HD * HD * 2);
    bf16* Whb  = (bf16*)alloc((size_t)3 * HD * HD * 2);
    bf16* fW1b = (bf16*)alloc((size_t)HD * HD * 2);
    bf16* fW2b = (bf16*)alloc((size_t)64 * HD * 2);
    int*  degB = (int*)alloc((size_t)n * 4);
    int*  rowsB= (int*)alloc((size_t)(n + 1) * 4);
    int*  rows2= (int*)alloc((size_t)(n + 1) * 4);
    int*  bsum = (int*)alloc(512);
    int*  curB = (int*)alloc((size_t)n * 4);
    int*  colB = (int*)alloc((size_t)E * 4);

    // x conversion (swizzled)
    int nU = n * 64;
    k_cvt_x<<<(nU + 255) / 256, 256, 0, stream>>>(x, (uint32_t*)xbf, nU);

    // fused weight conversion: 6 segments, 1 launch
    {
        Cvt6 a;
        int LHH = L * HD * HD, G = 3 * HD * HD, F1 = HD * HD, F2 = 64 * HD;
        a.seg[0] = {lW1, W1b};  a.seg[1] = {lW2, W2b};
        a.seg[2] = {Wih, Wib};  a.seg[3] = {Whh, Whb};
        a.seg[4] = {fW1, fW1b}; a.seg[5] = {fW2, fW2b};
        a.cum[0] = 0;
        a.cum[1] = LHH;         a.cum[2] = LHH * 2;
        a.cum[3] = LHH * 2 + G; a.cum[4] = LHH * 2 + G * 2;
        a.cum[5] = a.cum[4] + F1; a.cum[6] = a.cum[5] + F2;
        int total = a.cum[6];
        k_cvt6<<<(total + 255) / 256, 256, 0, stream>>>(a, total);
    }

    hipMemsetAsync(degB, 0, (size_t)n * 4, stream);
    hipMemsetAsync(hA, 0, (size_t)nPad * HD * 2, stream);

    // fused bound+count
    int nbB = (n + 1 + 255) / 256;
    int nbC = (E + 255) / 256;
    k_bc<<<nbB + nbC, 256, 0, stream>>>(dst + E, E, rows2, n, dst, degB, nbB);
    int nb = (n + 1023) / 1024;
    k_scan1<<<nb, 256, 0, stream>>>(degB, rowsB, bsum, n);
    k_scan2<<<1, 128, 0, stream>>>(bsum, nb);
    k_scan3<<<(n + 1 + 255) / 256, 256, 0, stream>>>(rowsB, bsum, curB, n, E);
    int nPerG = (n + 7) / 8;
    k_fillp<<<8 * ((E + 255) / 256), 256, 0, stream>>>(src, dst, curB, colB, E, nPerG);

    int nT64 = nPad / 64;
    int nT96 = nPad / 96;
    int gM = (nT64 < 512) ? nT64 : 512;   // 2 blocks/CU
    int gG = (nT96 < 256) ? nT96 : 256;   // 1 block/CU
    int nT16 = (n + 15) / 16;
    int gF = (nT16 + NTPB - 1) / NTPB;

    const bf16* curp = xbf;
    for (int l = 0; l < L; ++l){
        k_gather<<<(n + 3) / 4, 256, 0, stream>>>(curp, src + E, rows2, colB, rowsB, cin, n);
        k_mlp<<<gM, 512, 0, stream>>>(cin, cbn,
            W1b + (size_t)l * HD * HD, lb1 + l * HD,
            W2b + (size_t)l * HD * HD, lb2 + l * HD,
            gmm + l * HD, bta + l * HD, mun + l * HD, vrr + l * HD, nT64);
        k_gru<<<gG, 512, 0, stream>>>(cbn, hA, hB, Wib, Whb, bih, bhh, nT96);
        bf16* tmp = hA; hA = hB; hB = tmp;
        curp = hA;
    }
    k_final<<<gF, 256, 0, stream>>>(hA, fW1b, fb1, fW2b, fb2, (float*)d_out, nT16);
}